// Round 4
// baseline (512.508 us; speedup 1.0000x reference)
//
#include <hip/hip_runtime.h>
#include <hip/hip_bf16.h>

// ---------------------------------------------------------------------------
// MultiHeadAttention: B=4, T=1024, E=768, D=768, H=8, per-head full-width proj
// GEMMs: 256x256-tile 8-wave 4-phase pipelined bf16 MFMA kernel (gemm256),
// T2 LDS swizzle + counted prefetch (one syncthreads drain per K-tile) + T5.
// Fallback (small ws): proven R2/R3 chunked 128x128 path.
// ---------------------------------------------------------------------------

typedef __bf16 bf16x8 __attribute__((ext_vector_type(8)));
typedef float  f32x4  __attribute__((ext_vector_type(4)));
typedef short  s16x4  __attribute__((ext_vector_type(4)));

#define AS1 __attribute__((address_space(1)))
#define AS3 __attribute__((address_space(3)))

__device__ inline void gload_lds16(const void* g, void* l) {
  // async global->LDS, 16B per lane; LDS dest is wave-uniform base + lane*16
  __builtin_amdgcn_global_load_lds((AS1 const void*)g, (AS3 void*)l, 16, 0, 0);
}

__device__ inline unsigned short f2bf(float f) {  // RNE f32 -> bf16 bits
  union { float f; unsigned u; } c; c.f = f;
  unsigned r = c.u + 0x7FFF + ((c.u >> 16) & 1);
  return (unsigned short)(r >> 16);
}
__device__ inline float bf2f(unsigned short u) {
  return __uint_as_float(((unsigned)u) << 16);
}

// XCD-aware bijective remap (T1); valid when total blocks % 8 == 0
__device__ inline void swizzle_bid(int& bx, int& by, int& bz) {
  const int gx = gridDim.x, gy = gridDim.y, gz = gridDim.z;
  const int n = gx * gy * gz;
  if ((n & 7) == 0) {
    int lin = (blockIdx.z * gy + blockIdx.y) * gx + blockIdx.x;
    lin = (lin & 7) * (n >> 3) + (lin >> 3);
    bz = lin / (gx * gy);
    const int rem = lin - bz * gx * gy;
    by = rem / gx;
    bx = rem - by * gx;
  } else {
    bx = blockIdx.x; by = blockIdx.y; bz = blockIdx.z;
  }
}

// ---------------------------------------------------------------------------
// gemm256: C = scale * A * Bt^T (+ bias[z*biasZ+n]); A:[M,lda], Bt:[N,ldb] bf16
// 256x256 tile, BK=64, 512 threads (8 waves: 2M x 4N), per-wave 128x64 out.
// LDS (dynamic 128 KiB): As[2][256][64] | Bs[2][256][64], bf16.
// T2 swizzle: 16B unit u_phys = u_log ^ (row&7); staged via pre-swizzled
// global source (linear LDS dest), read back with the same XOR.
// Pipeline: stage tile t+1 (8 gload_lds) at t's P0; single __syncthreads()
// per K-tile at P3-end is the completion fence (vmcnt(0)+barrier).
// ---------------------------------------------------------------------------
__device__ __forceinline__ void stage_tile256(const unsigned short* __restrict__ G,
                                              int ld, int kbase,
                                              unsigned short* lbase,
                                              int tid, int wave) {
  const int sr = tid >> 3;                         // row 0..63 within chunk
  const int su = (tid & 7) ^ ((tid >> 3) & 7);     // pre-swizzled source unit
#pragma unroll
  for (int cc = 0; cc < 4; ++cc) {
    gload_lds16(G + (size_t)(cc * 64 + sr) * ld + kbase + su * 8,
                lbase + (cc * 64 + wave * 8) * 64);
  }
}

template<bool OUT_F32>
__global__ __launch_bounds__(512, 2)
void gemm256_kernel(const unsigned short* __restrict__ A,
                    const unsigned short* __restrict__ Bt,
                    void* __restrict__ Cout,
                    const float* __restrict__ bias,
                    int K, int lda, int ldb,
                    long long aZ, long long bZ,
                    long long cZhi, long long cZlo, int zShift,
                    long long cRowHi, int rowShift, int ldc,
                    long long biasZ, float scale)
{
  extern __shared__ unsigned short sm[];   // 65536 elems = 128 KiB

  int ntile, mtile, z;
  swizzle_bid(ntile, mtile, z);

  const int tid  = threadIdx.x;
  const int wave = tid >> 6;
  const int lane = tid & 63;
  const int wm = wave >> 2, wn = wave & 3;

  const unsigned short* Ab = A  + (size_t)z * aZ + (size_t)mtile * 256 * lda;
  const unsigned short* Bb = Bt + (size_t)z * bZ + (size_t)ntile * 256 * ldb;

  f32x4 acc[8][4] = {};

  const int nkt = K >> 6;
  // prologue: stage tile 0 into buffer 0
  stage_tile256(Ab, lda, 0, sm, tid, wave);
  stage_tile256(Bb, ldb, 0, sm + 32768, tid, wave);
  __syncthreads();

  const int rsel  = lane & 15;
  const int usel  = lane & 7;
  const int ubase = lane >> 4;                     // 0..3
  const int off0 = ((ubase) ^ usel) * 8;           // kk=0 swizzled elem offset
  const int off1 = ((4 | ubase) ^ usel) * 8;       // kk=1

  for (int kt = 0; kt < nkt; ++kt) {
    unsigned short* Ac = sm + (kt & 1) * 16384;
    unsigned short* Bc = sm + 32768 + (kt & 1) * 16384;
    unsigned short* An = sm + ((kt + 1) & 1) * 16384;
    unsigned short* Bn = sm + 32768 + ((kt + 1) & 1) * 16384;

    bf16x8 af[4], bfr[4];
    // ---- P0: mhalf 0, kk 0 (+ issue next-tile prefetch) ----
#pragma unroll
    for (int f = 0; f < 4; ++f) {
      af[f]  = *(const bf16x8*)&Ac[(wm * 128 + f * 16 + rsel) * 64 + off0];
      bfr[f] = *(const bf16x8*)&Bc[(wn * 64  + f * 16 + rsel) * 64 + off0];
    }
    if (kt + 1 < nkt) {
      stage_tile256(Ab, lda, (kt + 1) * 64, An, tid, wave);
      stage_tile256(Bb, ldb, (kt + 1) * 64, Bn, tid, wave);
    }
    __builtin_amdgcn_s_barrier();
    __builtin_amdgcn_s_setprio(1);
#pragma unroll
    for (int fm = 0; fm < 4; ++fm)
#pragma unroll
      for (int fn = 0; fn < 4; ++fn)
        acc[fm][fn] = __builtin_amdgcn_mfma_f32_16x16x32_bf16(af[fm], bfr[fn], acc[fm][fn], 0, 0, 0);
    __builtin_amdgcn_s_setprio(0);
    __builtin_amdgcn_s_barrier();

    // ---- P1: mhalf 1, kk 0 ----
#pragma unroll
    for (int f = 0; f < 4; ++f)
      af[f] = *(const bf16x8*)&Ac[(wm * 128 + 64 + f * 16 + rsel) * 64 + off0];
    __builtin_amdgcn_s_barrier();
    __builtin_amdgcn_s_setprio(1);
#pragma unroll
    for (int fm = 0; fm < 4; ++fm)
#pragma unroll
      for (int fn = 0; fn < 4; ++fn)
        acc[4 + fm][fn] = __builtin_amdgcn_mfma_f32_16x16x32_bf16(af[fm], bfr[fn], acc[4 + fm][fn], 0, 0, 0);
    __builtin_amdgcn_s_setprio(0);
    __builtin_amdgcn_s_barrier();

    // ---- P2: mhalf 0, kk 1 ----
#pragma unroll
    for (int f = 0; f < 4; ++f) {
      af[f]  = *(const bf16x8*)&Ac[(wm * 128 + f * 16 + rsel) * 64 + off1];
      bfr[f] = *(const bf16x8*)&Bc[(wn * 64  + f * 16 + rsel) * 64 + off1];
    }
    __builtin_amdgcn_s_barrier();
    __builtin_amdgcn_s_setprio(1);
#pragma unroll
    for (int fm = 0; fm < 4; ++fm)
#pragma unroll
      for (int fn = 0; fn < 4; ++fn)
        acc[fm][fn] = __builtin_amdgcn_mfma_f32_16x16x32_bf16(af[fm], bfr[fn], acc[fm][fn], 0, 0, 0);
    __builtin_amdgcn_s_setprio(0);
    __builtin_amdgcn_s_barrier();

    // ---- P3: mhalf 1, kk 1; syncthreads = vmcnt(0)+barrier fence ----
#pragma unroll
    for (int f = 0; f < 4; ++f)
      af[f] = *(const bf16x8*)&Ac[(wm * 128 + 64 + f * 16 + rsel) * 64 + off1];
    __builtin_amdgcn_s_barrier();
    __builtin_amdgcn_s_setprio(1);
#pragma unroll
    for (int fm = 0; fm < 4; ++fm)
#pragma unroll
      for (int fn = 0; fn < 4; ++fn)
        acc[4 + fm][fn] = __builtin_amdgcn_mfma_f32_16x16x32_bf16(af[fm], bfr[fn], acc[4 + fm][fn], 0, 0, 0);
    __builtin_amdgcn_s_setprio(0);
    __syncthreads();   // drains this wave's prefetch vmcnt + barrier: next
                       // tile's LDS writes complete & visible to all waves
  }

  // epilogue: C/D frag layout: col = lane&15, row = (lane>>4)*4 + j  [m89]
  const long long zoff = (long long)(z >> zShift) * cZhi
                       + (long long)(z & ((1 << zShift) - 1)) * cZlo;
#pragma unroll
  for (int fm = 0; fm < 8; ++fm) {
#pragma unroll
    for (int j = 0; j < 4; ++j) {
      const int m = mtile * 256 + wm * 128 + fm * 16 + (lane >> 4) * 4 + j;
      const long long rowoff = (long long)(m >> rowShift) * cRowHi
                             + (long long)(m & ((1 << rowShift) - 1)) * ldc;
#pragma unroll
      for (int fn = 0; fn < 4; ++fn) {
        const int n = ntile * 256 + wn * 64 + fn * 16 + (lane & 15);
        float v = acc[fm][fn][j] * scale;
        if (bias) v += bias[(size_t)z * biasZ + n];
        const long long cidx = zoff + rowoff + n;
        if (OUT_F32) ((float*)Cout)[cidx] = v;
        else ((unsigned short*)Cout)[cidx] = f2bf(v);
      }
    }
  }
}

// ---------------------------------------------------------------------------
// 128x128 GEMM (m97 structure) — fallback tier only
// ---------------------------------------------------------------------------
template<bool OUT_F32>
__global__ __launch_bounds__(256, 2)
void gemm_bt_kernel(const unsigned short* __restrict__ A,
                    const unsigned short* __restrict__ Bt,
                    void* __restrict__ Cout,
                    const float* __restrict__ bias,
                    int K, int lda, int ldb,
                    long long aZ, long long bZ,
                    long long cZhi, long long cZlo, int zShift,
                    long long cRowHi, int rowShift, int ldc,
                    long long biasZ, float scale)
{
  __shared__ unsigned short As[128 * 64];
  __shared__ unsigned short Bs[128 * 64];

  int ntile, mtile, z;
  swizzle_bid(ntile, mtile, z);

  const int tid  = threadIdx.x;
  const int wave = tid >> 6;
  const int lane = tid & 63;
  const int wm = wave >> 1, wn = wave & 1;

  const unsigned short* Ab = A  + (size_t)z * aZ + (size_t)mtile * 128 * lda;
  const unsigned short* Bb = Bt + (size_t)z * bZ + (size_t)ntile * 128 * ldb;

  const int rlane = lane >> 3;
  const int ck    = (lane & 7) * 8;

  f32x4 acc[4][4] = {};

  const int nkt = K >> 6;
  for (int kt = 0; kt < nkt; ++kt) {
    const int kbase = kt * 64;
    __syncthreads();
#pragma unroll
    for (int i = 0; i < 4; ++i) {
      const int r = wave * 32 + i * 8;
      gload_lds16(Ab + (size_t)(r + rlane) * lda + kbase + ck, &As[r * 64]);
      gload_lds16(Bb + (size_t)(r + rlane) * ldb + kbase + ck, &Bs[r * 64]);
    }
    __syncthreads();
#pragma unroll
    for (int kk = 0; kk < 2; ++kk) {
      const int koff = kk * 32 + (lane >> 4) * 8;
      bf16x8 af[4], bfr[4];
#pragma unroll
      for (int f = 0; f < 4; ++f) {
        af[f]  = *(const bf16x8*)&As[(wm * 64 + f * 16 + (lane & 15)) * 64 + koff];
        bfr[f] = *(const bf16x8*)&Bs[(wn * 64 + f * 16 + (lane & 15)) * 64 + koff];
      }
#pragma unroll
      for (int fm = 0; fm < 4; ++fm)
#pragma unroll
        for (int fn = 0; fn < 4; ++fn)
          acc[fm][fn] = __builtin_amdgcn_mfma_f32_16x16x32_bf16(af[fm], bfr[fn], acc[fm][fn], 0, 0, 0);
    }
  }

  const long long zoff = (long long)(z >> zShift) * cZhi
                       + (long long)(z & ((1 << zShift) - 1)) * cZlo;
#pragma unroll
  for (int fm = 0; fm < 4; ++fm) {
#pragma unroll
    for (int j = 0; j < 4; ++j) {
      const int m = mtile * 128 + wm * 64 + fm * 16 + (lane >> 4) * 4 + j;
      const long long rowoff = (long long)(m >> rowShift) * cRowHi
                             + (long long)(m & ((1 << rowShift) - 1)) * ldc;
#pragma unroll
      for (int fn = 0; fn < 4; ++fn) {
        const int n = ntile * 128 + wn * 64 + fn * 16 + (lane & 15);
        float v = acc[fm][fn][j] * scale;
        if (bias) v += bias[(size_t)z * biasZ + n];
        const long long cidx = zoff + rowoff + n;
        if (OUT_F32) ((float*)Cout)[cidx] = v;
        else ((unsigned short*)Cout)[cidx] = f2bf(v);
      }
    }
  }
}

// fp32 [Z][R][C] -> bf16 [Z][C][R] tile transpose+convert
__global__ void transpose_conv_kernel(const float* __restrict__ in,
                                      unsigned short* __restrict__ out,
                                      int R, int C)
{
  __shared__ float tile[32][33];
  const size_t zo = (size_t)blockIdx.z * R * C;
  const int c0 = blockIdx.x * 32, r0 = blockIdx.y * 32;
  const int tx = threadIdx.x, ty = threadIdx.y;
#pragma unroll
  for (int i = ty; i < 32; i += 8)
    tile[i][tx] = in[zo + (size_t)(r0 + i) * C + c0 + tx];
  __syncthreads();
#pragma unroll
  for (int i = ty; i < 32; i += 8)
    out[zo + (size_t)(c0 + i) * R + r0 + tx] = f2bf(tile[tx][i]);
}

// bf16 [Z][R][C] -> bf16 [Z][C][R]
__global__ void transpose_bf16_kernel(const unsigned short* __restrict__ in,
                                      unsigned short* __restrict__ out,
                                      int R, int C)
{
  __shared__ unsigned short tile[32][33];
  const size_t zo = (size_t)blockIdx.z * R * C;
  const int c0 = blockIdx.x * 32, r0 = blockIdx.y * 32;
  const int tx = threadIdx.x, ty = threadIdx.y;
#pragma unroll
  for (int i = ty; i < 32; i += 8)
    tile[i][tx] = in[zo + (size_t)(r0 + i) * C + c0 + tx];
  __syncthreads();
#pragma unroll
  for (int i = ty; i < 32; i += 8)
    out[zo + (size_t)(c0 + i) * R + r0 + tx] = tile[tx][i];
}

__global__ void convert_f32_bf16_kernel(const float* __restrict__ in,
                                        unsigned short* __restrict__ out, int n4)
{
  const int i = blockIdx.x * blockDim.x + threadIdx.x;
  if (i < n4) {
    const float4 f = ((const float4*)in)[i];
    s16x4 o;
    o[0] = (short)f2bf(f.x); o[1] = (short)f2bf(f.y);
    o[2] = (short)f2bf(f.z); o[3] = (short)f2bf(f.w);
    ((s16x4*)out)[i] = o;
  }
}

__global__ void bosum_kernel(const float* __restrict__ bo, float* __restrict__ bos)
{
  const int e = blockIdx.x * blockDim.x + threadIdx.x;
  if (e < 768) {
    float s = 0.f;
#pragma unroll
    for (int h = 0; h < 8; ++h) s += bo[h * 768 + e];
    bos[e] = s;
  }
}

// concat bq,bk,bv -> bqkv[24][768] (z = proj*8 + h)
__global__ void bconcat_kernel(const float* __restrict__ bq,
                               const float* __restrict__ bk,
                               const float* __restrict__ bv,
                               float* __restrict__ bqkv)
{
  const int i = blockIdx.x * blockDim.x + threadIdx.x;
  if (i < 24 * 768) {
    const int z = i / 768, d = i - z * 768;
    const float* src = (z < 8) ? bq : (z < 16) ? bk : bv;
    bqkv[i] = src[(z & 7) * 768 + d];
  }
}

// out[i] = sum_{kz<8} partials[kz][i] + bos[col]
__global__ void reduce8_kernel(const float* __restrict__ partials,
                               const float* __restrict__ bos,
                               float* __restrict__ out, int n4)
{
  const int i = blockIdx.x * blockDim.x + threadIdx.x;
  if (i < n4) {
    const long long stride4 = 4096LL * 768 / 4;
    float4 s = ((const float4*)partials)[i];
#pragma unroll
    for (int k2 = 1; k2 < 8; ++k2) {
      float4 p = ((const float4*)partials)[i + k2 * stride4];
      s.x += p.x; s.y += p.y; s.z += p.z; s.w += p.w;
    }
    const int col = (i * 4) % 768;
    const float4 b4 = *(const float4*)&bos[col];
    s.x += b4.x; s.y += b4.y; s.z += b4.z; s.w += b4.w;
    ((float4*)out)[i] = s;
  }
}

// in-place row softmax on bf16 [rows][1024]; one block (256 thr) per row
__global__ __launch_bounds__(256)
void softmax_kernel(unsigned short* __restrict__ S)
{
  const size_t row = blockIdx.x;
  unsigned short* p = S + row * 1024;
  const int t = threadIdx.x;

  s16x4 raw = *((const s16x4*)p + t);
  float v[4];
#pragma unroll
  for (int j = 0; j < 4; ++j) v[j] = bf2f((unsigned short)raw[j]);

  float mx = fmaxf(fmaxf(v[0], v[1]), fmaxf(v[2], v[3]));
#pragma unroll
  for (int o = 1; o < 64; o <<= 1) mx = fmaxf(mx, __shfl_xor(mx, o));

  __shared__ float red[8];
  if ((t & 63) == 0) red[t >> 6] = mx;
  __syncthreads();
  mx = fmaxf(fmaxf(red[0], red[1]), fmaxf(red[2], red[3]));

  float e[4], s = 0.f;
#pragma unroll
  for (int j = 0; j < 4; ++j) { e[j] = __expf(v[j] - mx); s += e[j]; }
#pragma unroll
  for (int o = 1; o < 64; o <<= 1) s += __shfl_xor(s, o);
  if ((t & 63) == 0) red[4 + (t >> 6)] = s;
  __syncthreads();
  s = red[4] + red[5] + red[6] + red[7];
  const float inv = 1.0f / s;

  s16x4 outv;
#pragma unroll
  for (int j = 0; j < 4; ++j) outv[j] = (short)f2bf(e[j] * inv);
  *((s16x4*)p + t) = outv;
}

// ---------------------------------------------------------------------------
extern "C" void kernel_launch(void* const* d_in, const int* in_sizes, int n_in,
                              void* d_out, int out_size, void* d_ws, size_t ws_size,
                              hipStream_t stream)
{
  (void)in_sizes; (void)n_in; (void)out_size;
  constexpr int Bb = 4, T = 1024, E = 768, D = 768, H = 8;
  constexpr int HD = H * D;                           // 6144
  constexpr long long TD = (long long)T * D;          // 786432
  constexpr long long TT = (long long)T * T;          // 1048576
  constexpr long long DE = (long long)D * E;          // 589824
  constexpr long long DT = (long long)D * T;          // 786432
  constexpr long long BHTD = (long long)Bb * H * T * D;  // 25165824
  constexpr long long HTD = (long long)H * TD;        // 6291456
  constexpr float SCALE = 0.03608439182435161f;       // 1/sqrt(E)

  const float* x  = (const float*)d_in[0];
  const float* wq = (const float*)d_in[1];
  const float* bq = (const float*)d_in[2];
  const float* wk = (const float*)d_in[3];
  const float* bk = (const float*)d_in[4];
  const float* wv = (const float*)d_in[5];
  const float* bv = (const float*)d_in[6];
  const float* wo = (const float*)d_in[7];
  const float* bo = (const float*)d_in[8];
  float* out = (float*)d_out;

  unsigned char* wsb = (unsigned char*)d_ws;
  const dim3 tb32(32, 8);

  // allow 128 KiB dynamic LDS for gemm256 (deterministic; capture-safe)
  hipFuncSetAttribute(reinterpret_cast<const void*>(gemm256_kernel<false>),
                      hipFuncAttributeMaxDynamicSharedMemorySize, 131072);
  hipFuncSetAttribute(reinterpret_cast<const void*>(gemm256_kernel<true>),
                      hipFuncAttributeMaxDynamicSharedMemorySize, 131072);

  // ---- ALL32 tier peak footprint: 245,443,584 B ----
  if (ws_size >= 245443584ULL + 4096ULL) {
    unsigned short* woT   = (unsigned short*)(wsb + 0);            //  9,437,184
    float*          bos   = (float*)(wsb + 9437184);               //      3,072
    float*          bqkv  = (float*)(wsb + 9440256);               //     73,728
    unsigned short* vT    = (unsigned short*)(wsb + 9513984);      // 50,331,648
    unsigned short* qkv   = (unsigned short*)(wsb + 59845632);     // 3x 50,331,648
    unsigned short* q     = qkv;
    unsigned short* k     = qkv + BHTD;
    unsigned short* v     = qkv + 2 * BHTD;
    unsigned short* xb    = (unsigned short*)(wsb + 210840576);    //  6,291,456
    unsigned short* wqkvT = (unsigned short*)(wsb + 217132032);    // 28,311,552
    unsigned short* S     = v;          // overlays dead v+xb+wqkvT (67,108,864)
    float*          part  = (float*)k;  // 8x12.6MB=100,663,296 overlays dead k/v/S
    unsigned short* z2    = q;          // overlays dead q

    // --- prep ---
    convert_f32_bf16_kernel<<<3072, 256, 0, stream>>>(x, xb, Bb * T * E / 4);
    transpose_conv_kernel<<<dim3(24, 24, 8), tb32, 0, stream>>>(wq, wqkvT, E, D);
    transpose_conv_kernel<<<dim3(24, 24, 8), tb32, 0, stream>>>(wk, wqkvT + 8 * DE, E, D);
    transpose_conv_kernel<<<dim3(24, 24, 8), tb32, 0, stream>>>(wv, wqkvT + 16 * DE, E, D);
    transpose_conv_kernel<<<dim3(24, 192, 1), tb32, 0, stream>>>(wo, woT, HD, E);
    bosum_kernel<<<3, 256, 0, stream>>>(bo, bos);
    bconcat_kernel<<<72, 256, 0, stream>>>(bq, bk, bv, bqkv);

    // --- fused QKV: z = proj*8 + h ---
    gemm256_kernel<false><<<dim3(3, 16, 24), 512, 131072, stream>>>(
        xb, wqkvT, qkv, bqkv, E, E, E,
        0LL, DE, BHTD, TD, 3, HTD, 10, D, 768LL, 1.0f);

    // --- v -> vT [B,H,D,T] ---
    transpose_bf16_kernel<<<dim3(24, 32, 32), tb32, 0, stream>>>(v, vT, T, D);

    // --- S = scale * q k^T  [BH,T,T] ---
    gemm256_kernel<false><<<dim3(4, 4, 32), 512, 131072, stream>>>(
        q, k, S, nullptr, D, D, D,
        TD, TD, TT, 0LL, 0, 0LL, 30, T, 0LL, SCALE);

    // --- softmax all rows ---
    softmax_kernel<<<Bb * H * T, 256, 0, stream>>>(S);

    // --- z2[b,t,h*D+n] = P v : z = b*8+h ---
    gemm256_kernel<false><<<dim3(3, 4, 32), 512, 131072, stream>>>(
        S, vT, z2, nullptr, T, T, T,
        TT, DT, (long long)T * HD, (long long)D, 3, 0LL, 30, HD, 0LL, 1.0f);

    // --- out-proj split-K=8: partials[kz][4096][768] fp32 ---
    gemm256_kernel<true><<<dim3(3, 16, 8), 512, 131072, stream>>>(
        z2, woT, part, nullptr, 768, HD, HD,
        768LL, 768LL, 3145728LL, 0LL, 0, 0LL, 30, E, 0LL, 1.0f);
    reduce8_kernel<<<3072, 256, 0, stream>>>(part, bos, out, 4096 * 768 / 4);
    return;
  }

  // ---------------- fallback: proven R2 chunked path (128x128 GEMM) --------
  const size_t FIXED = 84937728ULL;
  const size_t PERCH = 8388608ULL;
  int CH = 8;
  while (CH > 1 && FIXED + (size_t)CH * PERCH > ws_size) CH >>= 1;

  size_t off = 0;
  auto carve = [&](size_t bytes) -> void* {
    void* p = wsb + off;
    off += (bytes + 255) & ~(size_t)255;
    return p;
  };
  unsigned short* xb  = (unsigned short*)carve((size_t)Bb * T * E * 2);
  unsigned short* wqT = (unsigned short*)carve((size_t)H * D * E * 2);
  unsigned short* wkT = (unsigned short*)carve((size_t)H * D * E * 2);
  unsigned short* wvT = (unsigned short*)carve((size_t)H * D * E * 2);
  float*          bos = (float*)carve(E * 4);
  unsigned short* z2  = (unsigned short*)carve((size_t)Bb * T * HD * 2);
  unsigned short* qc  = (unsigned short*)carve((size_t)CH * T * D * 2);
  unsigned short* kc  = (unsigned short*)carve((size_t)CH * T * D * 2);
  unsigned short* vc  = (unsigned short*)carve((size_t)CH * T * D * 2);
  unsigned short* vTc = (unsigned short*)carve((size_t)CH * D * T * 2);
  unsigned short* Sc  = (unsigned short*)carve((size_t)CH * T * T * 2);
  unsigned short* woT = wqT;  // wqT dead after chunk loop

  convert_f32_bf16_kernel<<<3072, 256, 0, stream>>>(x, xb, Bb * T * E / 4);
  transpose_conv_kernel<<<dim3(24, 24, 8), tb32, 0, stream>>>(wq, wqT, E, D);
  transpose_conv_kernel<<<dim3(24, 24, 8), tb32, 0, stream>>>(wk, wkT, E, D);
  transpose_conv_kernel<<<dim3(24, 24, 8), tb32, 0, stream>>>(wv, wvT, E, D);
  bosum_kernel<<<3, 256, 0, stream>>>(bo, bos);

  const int nchunks = (Bb * H) / CH;
  for (int c = 0; c < nchunks; ++c) {
    const int z0 = c * CH;
    const int b  = z0 >> 3;
    const int h0 = z0 & 7;
    const unsigned short* xbb = xb + (size_t)b * T * E;

    gemm_bt_kernel<false><<<dim3(6, 8, CH), 256, 0, stream>>>(
        xbb, wqT + (size_t)h0 * DE, qc, bq + (size_t)h0 * D, E, E, E,
        0LL, DE, TD, 0LL, 0, 0LL, 30, D, (long long)D, 1.0f);
    gemm_bt_kernel<false><<<dim3(6, 8, CH), 256, 0, stream>>>(
        xbb, wkT + (size_t)h0 * DE, kc, bk + (size_t)h0 * D, E, E, E,
        0LL, DE, TD, 0LL, 0, 0LL, 30, D, (long long)D, 1.0f);
    gemm_bt_kernel<false><<<dim3(6, 8, CH), 256, 0, stream>>>(
        xbb, wvT + (size_t)h0 * DE, vc, bv + (size_t)h0 * D, E, E, E,
        0LL, DE, TD, 0LL, 0, 0LL, 30, D, (long long)D, 1.0f);

    transpose_bf16_kernel<<<dim3(24, 32, CH), tb32, 0, stream>>>(vc, vTc, T, D);

    gemm_bt_kernel<false><<<dim3(8, 8, CH), 256, 0, stream>>>(
        qc, kc, Sc, nullptr, D, D, D,
        TD, TD, TT, 0LL, 0, 0LL, 30, T, 0LL, SCALE);

    softmax_kernel<<<CH * T, 256, 0, stream>>>(Sc);

    gemm_bt_kernel<false><<<dim3(6, 8, CH), 256, 0, stream>>>(
        Sc, vTc, z2 + (size_t)b * T * HD + (size_t)h0 * D, nullptr, T, T, T,
        TT, DT, (long long)D, 0LL, 0, 0LL, 30, HD, 0LL, 1.0f);
  }

  transpose_conv_kernel<<<dim3(24, 192, 1), tb32, 0, stream>>>(wo, woT, HD, E);
  gemm_bt_kernel<true><<<dim3(6, 32, 1), 256, 0, stream>>>(
      z2, woT, out, bos, HD, HD, HD,
      0LL, 0LL, 0LL, 0LL, 0, 0LL, 30, E, 0LL, 1.0f);
}

// Round 5
// 494.326 us; speedup vs baseline: 1.0368x; 1.0368x over previous
//
#include <hip/hip_runtime.h>
#include <hip/hip_bf16.h>

// ---------------------------------------------------------------------------
// MultiHeadAttention: B=4, T=1024, E=768, D=768, H=8, per-head full-width proj
// gemm256: 256x256 tile, 8 waves, BK=64, T2 XOR-swizzle, T4 counted-vmcnt
// pipeline (A 3-buf / B 2-buf, fence = vmcnt(4), never 0), T5 setprio, T1.
// Fallbacks: 128x128 m97-style GEMM (attr failure), chunked path (small ws).
// ---------------------------------------------------------------------------

typedef __bf16 bf16x8 __attribute__((ext_vector_type(8)));
typedef float  f32x4  __attribute__((ext_vector_type(4)));
typedef short  s16x4  __attribute__((ext_vector_type(4)));

#define AS1 __attribute__((address_space(1)))
#define AS3 __attribute__((address_space(3)))

__device__ inline void gload_lds16(const void* g, void* l) {
  // async global->LDS, 16B/lane; LDS dest wave-uniform base + lane*16
  __builtin_amdgcn_global_load_lds((AS1 const void*)g, (AS3 void*)l, 16, 0, 0);
}

__device__ inline unsigned short f2bf(float f) {  // RNE f32 -> bf16 bits
  union { float f; unsigned u; } c; c.f = f;
  unsigned r = c.u + 0x7FFF + ((c.u >> 16) & 1);
  return (unsigned short)(r >> 16);
}
__device__ inline float bf2f(unsigned short u) {
  return __uint_as_float(((unsigned)u) << 16);
}

// XCD-aware bijective remap (T1); valid when total blocks % 8 == 0
__device__ inline void swizzle_bid(int& bx, int& by, int& bz) {
  const int gx = gridDim.x, gy = gridDim.y, gz = gridDim.z;
  const int n = gx * gy * gz;
  if ((n & 7) == 0) {
    int lin = (blockIdx.z * gy + blockIdx.y) * gx + blockIdx.x;
    lin = (lin & 7) * (n >> 3) + (lin >> 3);
    bz = lin / (gx * gy);
    const int rem = lin - bz * gx * gy;
    by = rem / gx;
    bx = rem - by * gx;
  } else {
    bx = blockIdx.x; by = blockIdx.y; bz = blockIdx.z;
  }
}

// stage 2 chunks (128 rows) of a 256x64 bf16 tile; global source pre-swizzled
// (unit su = u ^ (row&7)) so linear gload_lds dest yields swizzled LDS.
__device__ __forceinline__ void stage2(const unsigned short* __restrict__ G,
                                       int ld, int kbase,
                                       unsigned short* lbase,
                                       int tid, int wave, int cc0) {
  const int sr = tid >> 3;                       // row 0..63 within chunk
  const int su = (tid & 7) ^ ((tid >> 3) & 7);   // pre-swizzled source unit
#pragma unroll
  for (int cc = cc0; cc < cc0 + 2; ++cc)
    gload_lds16(G + (size_t)(cc * 64 + sr) * ld + kbase + su * 8,
                lbase + (cc * 64 + wave * 8) * 64);
}
__device__ __forceinline__ void stage4(const unsigned short* __restrict__ G,
                                       int ld, int kbase,
                                       unsigned short* lbase,
                                       int tid, int wave) {
  stage2(G, ld, kbase, lbase, tid, wave, 0);
  stage2(G, ld, kbase, lbase, tid, wave, 2);
}

#define TILE_FENCE4() do {                                  \
    asm volatile("s_waitcnt vmcnt(4)" ::: "memory");        \
    __builtin_amdgcn_sched_barrier(0);                      \
    __builtin_amdgcn_s_barrier();                           \
    __builtin_amdgcn_sched_barrier(0);                      \
  } while (0)

// ---------------------------------------------------------------------------
// gemm256: C = scale * A * Bt^T (+ bias[z*biasZ+n]); A:[M,lda], Bt:[N,ldb] bf16
// Grid (N/256, M/256, Z), 512 threads (8 waves: 2M x 4N), wave out 128x64.
// LDS 160 KiB dynamic: A slots {0,16384,32768} (t%3), B slots {49152,65536}
// (t&1), each 256x64 bf16. Requires nkt >= 2.
// Pipeline: during tile t stage B(t+1) [4 loads] then A(t+2) [4 loads];
// tile fence = vmcnt(4) (A(t+2) stays in flight) + s_barrier.
// ---------------------------------------------------------------------------
template<bool OUT_F32>
__global__ __launch_bounds__(512, 2)
void gemm256_kernel(const unsigned short* __restrict__ A,
                    const unsigned short* __restrict__ Bt,
                    void* __restrict__ Cout,
                    const float* __restrict__ bias,
                    int K, int lda, int ldb,
                    long long aZ, long long bZ,
                    long long cZhi, long long cZlo, int zShift,
                    long long cRowHi, int rowShift, int ldc,
                    long long biasZ, float scale)
{
  extern __shared__ unsigned short sm[];   // 81920 elems = 160 KiB

  int ntile, mtile, z;
  swizzle_bid(ntile, mtile, z);

  const int tid  = threadIdx.x;
  const int wave = tid >> 6;
  const int lane = tid & 63;
  const int wm = wave >> 2, wn = wave & 3;

  const unsigned short* Ab = A  + (size_t)z * aZ + (size_t)mtile * 256 * lda;
  const unsigned short* Bb = Bt + (size_t)z * bZ + (size_t)ntile * 256 * ldb;

  f32x4 acc[8][4] = {};

  const int nkt = K >> 6;
  int a0 = 0, a1 = 16384, a2 = 32768;   // A slot rotation (tile t -> a0)
  int bcur = 0;                         // B slot (tile t -> bcur)

  // prologue: A(0)->a0, B(0)->b0, A(1)->a1; drain A0+B0, keep A1 in flight
  stage4(Ab, lda, 0, sm + a0, tid, wave);
  stage4(Bb, ldb, 0, sm + 49152, tid, wave);
  if (nkt > 1) {
    stage4(Ab, lda, 64, sm + a1, tid, wave);
    TILE_FENCE4();
  } else {
    asm volatile("s_waitcnt vmcnt(0)" ::: "memory");
    __builtin_amdgcn_sched_barrier(0);
    __builtin_amdgcn_s_barrier();
  }

  const int rsel  = lane & 15;
  const int usel  = lane & 7;
  const int ubase = lane >> 4;                   // logical 16B unit 0..3
  const int off0 = ((ubase) ^ usel) * 8;         // kk=0 swizzled elem offset
  const int off1 = ((4 | ubase) ^ usel) * 8;     // kk=1

  for (int t = 0; t < nkt; ++t) {
    const unsigned short* Ac = sm + a0;
    const unsigned short* Bc = sm + 49152 + bcur * 16384;
    unsigned short* Bn  = sm + 49152 + (bcur ^ 1) * 16384;
    unsigned short* An2 = sm + a2;

    bf16x8 af[4], bfr[4];
    // ---- phase0: mh=0, kk=0 ; stage B(t+1) ----
#pragma unroll
    for (int f = 0; f < 4; ++f) {
      af[f]  = *(const bf16x8*)&Ac[(wm * 128 + f * 16 + rsel) * 64 + off0];
      bfr[f] = *(const bf16x8*)&Bc[(wn * 64  + f * 16 + rsel) * 64 + off0];
    }
    if (t + 1 < nkt) stage4(Bb, ldb, (t + 1) * 64, Bn, tid, wave);
    __builtin_amdgcn_s_barrier();
    __builtin_amdgcn_s_setprio(1);
#pragma unroll
    for (int fm = 0; fm < 4; ++fm)
#pragma unroll
      for (int fn = 0; fn < 4; ++fn)
        acc[fm][fn] = __builtin_amdgcn_mfma_f32_16x16x32_bf16(af[fm], bfr[fn], acc[fm][fn], 0, 0, 0);
    __builtin_amdgcn_s_setprio(0);
    __builtin_amdgcn_s_barrier();

    // ---- phase1: mh=1, kk=0 ; stage A(t+2) chunks 0-1 ----
#pragma unroll
    for (int f = 0; f < 4; ++f)
      af[f] = *(const bf16x8*)&Ac[(wm * 128 + 64 + f * 16 + rsel) * 64 + off0];
    if (t + 2 < nkt) stage2(Ab, lda, (t + 2) * 64, An2, tid, wave, 0);
    __builtin_amdgcn_s_barrier();
    __builtin_amdgcn_s_setprio(1);
#pragma unroll
    for (int fm = 0; fm < 4; ++fm)
#pragma unroll
      for (int fn = 0; fn < 4; ++fn)
        acc[4 + fm][fn] = __builtin_amdgcn_mfma_f32_16x16x32_bf16(af[fm], bfr[fn], acc[4 + fm][fn], 0, 0, 0);
    __builtin_amdgcn_s_setprio(0);
    __builtin_amdgcn_s_barrier();

    // ---- phase2: mh=0, kk=1 ; stage A(t+2) chunks 2-3 ----
#pragma unroll
    for (int f = 0; f < 4; ++f) {
      af[f]  = *(const bf16x8*)&Ac[(wm * 128 + f * 16 + rsel) * 64 + off1];
      bfr[f] = *(const bf16x8*)&Bc[(wn * 64  + f * 16 + rsel) * 64 + off1];
    }
    if (t + 2 < nkt) stage2(Ab, lda, (t + 2) * 64, An2, tid, wave, 2);
    __builtin_amdgcn_s_barrier();
    __builtin_amdgcn_s_setprio(1);
#pragma unroll
    for (int fm = 0; fm < 4; ++fm)
#pragma unroll
      for (int fn = 0; fn < 4; ++fn)
        acc[fm][fn] = __builtin_amdgcn_mfma_f32_16x16x32_bf16(af[fm], bfr[fn], acc[fm][fn], 0, 0, 0);
    __builtin_amdgcn_s_setprio(0);
    __builtin_amdgcn_s_barrier();

    // ---- phase3: mh=1, kk=1 ; then counted tile fence ----
#pragma unroll
    for (int f = 0; f < 4; ++f)
      af[f] = *(const bf16x8*)&Ac[(wm * 128 + 64 + f * 16 + rsel) * 64 + off1];
    __builtin_amdgcn_s_barrier();
    __builtin_amdgcn_s_setprio(1);
#pragma unroll
    for (int fm = 0; fm < 4; ++fm)
#pragma unroll
      for (int fn = 0; fn < 4; ++fn)
        acc[4 + fm][fn] = __builtin_amdgcn_mfma_f32_16x16x32_bf16(af[fm], bfr[fn], acc[4 + fm][fn], 0, 0, 0);
    __builtin_amdgcn_s_setprio(0);
    TILE_FENCE4();   // vmcnt(4): drains A(t+1)+B(t+1), keeps A(t+2) in flight

    const int tmp = a0; a0 = a1; a1 = a2; a2 = tmp;   // rotate A slots
    bcur ^= 1;
  }

  // epilogue: C/D frag layout: col = lane&15, row = (lane>>4)*4 + j  [m89]
  const long long zoff = (long long)(z >> zShift) * cZhi
                       + (long long)(z & ((1 << zShift) - 1)) * cZlo;
#pragma unroll
  for (int fm = 0; fm < 8; ++fm) {
#pragma unroll
    for (int j = 0; j < 4; ++j) {
      const int m = mtile * 256 + wm * 128 + fm * 16 + (lane >> 4) * 4 + j;
      const long long rowoff = (long long)(m >> rowShift) * cRowHi
                             + (long long)(m & ((1 << rowShift) - 1)) * ldc;
#pragma unroll
      for (int fn = 0; fn < 4; ++fn) {
        const int n = ntile * 256 + wn * 64 + fn * 16 + (lane & 15);
        float v = acc[fm][fn][j] * scale;
        if (bias) v += bias[(size_t)z * biasZ + n];
        const long long cidx = zoff + rowoff + n;
        if (OUT_F32) ((float*)Cout)[cidx] = v;
        else ((unsigned short*)Cout)[cidx] = f2bf(v);
      }
    }
  }
}

// ---------------------------------------------------------------------------
// 128x128 GEMM (m97 structure) — fallback
// ---------------------------------------------------------------------------
template<bool OUT_F32>
__global__ __launch_bounds__(256, 2)
void gemm_bt_kernel(const unsigned short* __restrict__ A,
                    const unsigned short* __restrict__ Bt,
                    void* __restrict__ Cout,
                    const float* __restrict__ bias,
                    int K, int lda, int ldb,
                    long long aZ, long long bZ,
                    long long cZhi, long long cZlo, int zShift,
                    long long cRowHi, int rowShift, int ldc,
                    long long biasZ, float scale)
{
  __shared__ unsigned short As[128 * 64];
  __shared__ unsigned short Bs[128 * 64];

  int ntile, mtile, z;
  swizzle_bid(ntile, mtile, z);

  const int tid  = threadIdx.x;
  const int wave = tid >> 6;
  const int lane = tid & 63;
  const int wm = wave >> 1, wn = wave & 1;

  const unsigned short* Ab = A  + (size_t)z * aZ + (size_t)mtile * 128 * lda;
  const unsigned short* Bb = Bt + (size_t)z * bZ + (size_t)ntile * 128 * ldb;

  const int rlane = lane >> 3;
  const int ck    = (lane & 7) * 8;

  f32x4 acc[4][4] = {};

  const int nkt = K >> 6;
  for (int kt = 0; kt < nkt; ++kt) {
    const int kbase = kt * 64;
    __syncthreads();
#pragma unroll
    for (int i = 0; i < 4; ++i) {
      const int r = wave * 32 + i * 8;
      gload_lds16(Ab + (size_t)(r + rlane) * lda + kbase + ck, &As[r * 64]);
      gload_lds16(Bb + (size_t)(r + rlane) * ldb + kbase + ck, &Bs[r * 64]);
    }
    __syncthreads();
#pragma unroll
    for (int kk = 0; kk < 2; ++kk) {
      const int koff = kk * 32 + (lane >> 4) * 8;
      bf16x8 af[4], bfr[4];
#pragma unroll
      for (int f = 0; f < 4; ++f) {
        af[f]  = *(const bf16x8*)&As[(wm * 64 + f * 16 + (lane & 15)) * 64 + koff];
        bfr[f] = *(const bf16x8*)&Bs[(wn * 64 + f * 16 + (lane & 15)) * 64 + koff];
      }
#pragma unroll
      for (int fm = 0; fm < 4; ++fm)
#pragma unroll
        for (int fn = 0; fn < 4; ++fn)
          acc[fm][fn] = __builtin_amdgcn_mfma_f32_16x16x32_bf16(af[fm], bfr[fn], acc[fm][fn], 0, 0, 0);
    }
  }

  const long long zoff = (long long)(z >> zShift) * cZhi
                       + (long long)(z & ((1 << zShift) - 1)) * cZlo;
#pragma unroll
  for (int fm = 0; fm < 4; ++fm) {
#pragma unroll
    for (int j = 0; j < 4; ++j) {
      const int m = mtile * 128 + wm * 64 + fm * 16 + (lane >> 4) * 4 + j;
      const long long rowoff = (long long)(m >> rowShift) * cRowHi
                             + (long long)(m & ((1 << rowShift) - 1)) * ldc;
#pragma unroll
      for (int fn = 0; fn < 4; ++fn) {
        const int n = ntile * 128 + wn * 64 + fn * 16 + (lane & 15);
        float v = acc[fm][fn][j] * scale;
        if (bias) v += bias[(size_t)z * biasZ + n];
        const long long cidx = zoff + rowoff + n;
        if (OUT_F32) ((float*)Cout)[cidx] = v;
        else ((unsigned short*)Cout)[cidx] = f2bf(v);
      }
    }
  }
}

// fp32 [Z][R][C] -> bf16 [Z][C][R] tile transpose+convert
__global__ void transpose_conv_kernel(const float* __restrict__ in,
                                      unsigned short* __restrict__ out,
                                      int R, int C)
{
  __shared__ float tile[32][33];
  const size_t zo = (size_t)blockIdx.z * R * C;
  const int c0 = blockIdx.x * 32, r0 = blockIdx.y * 32;
  const int tx = threadIdx.x, ty = threadIdx.y;
#pragma unroll
  for (int i = ty; i < 32; i += 8)
    tile[i][tx] = in[zo + (size_t)(r0 + i) * C + c0 + tx];
  __syncthreads();
#pragma unroll
  for (int i = ty; i < 32; i += 8)
    out[zo + (size_t)(c0 + i) * R + r0 + tx] = f2bf(tile[tx][i]);
}

// bf16 [Z][R][C] -> bf16 [Z][C][R]
__global__ void transpose_bf16_kernel(const unsigned short* __restrict__ in,
                                      unsigned short* __restrict__ out,
                                      int R, int C)
{
  __shared__ unsigned short tile[32][33];
  const size_t zo = (size_t)blockIdx.z * R * C;
  const int c0 = blockIdx.x * 32, r0 = blockIdx.y * 32;
  const int tx = threadIdx.x, ty = threadIdx.y;
#pragma unroll
  for (int i = ty; i < 32; i += 8)
    tile[i][tx] = in[zo + (size_t)(r0 + i) * C + c0 + tx];
  __syncthreads();
#pragma unroll
  for (int i = ty; i < 32; i += 8)
    out[zo + (size_t)(c0 + i) * R + r0 + tx] = tile[tx][i];
}

__global__ void convert_f32_bf16_kernel(const float* __restrict__ in,
                                        unsigned short* __restrict__ out, int n4)
{
  const int i = blockIdx.x * blockDim.x + threadIdx.x;
  if (i < n4) {
    const float4 f = ((const float4*)in)[i];
    s16x4 o;
    o[0] = (short)f2bf(f.x); o[1] = (short)f2bf(f.y);
    o[2] = (short)f2bf(f.z); o[3] = (short)f2bf(f.w);
    ((s16x4*)out)[i] = o;
  }
}

__global__ void bosum_kernel(const float* __restrict__ bo, float* __restrict__ bos)
{
  const int e = blockIdx.x * blockDim.x + threadIdx.x;
  if (e < 768) {
    float s = 0.f;
#pragma unroll
    for (int h = 0; h < 8; ++h) s += bo[h * 768 + e];
    bos[e] = s;
  }
}

// concat bq,bk,bv -> bqkv[24][768] (z = proj*8 + h)
__global__ void bconcat_kernel(const float* __restrict__ bq,
                               const float* __restrict__ bk,
                               const float* __restrict__ bv,
                               float* __restrict__ bqkv)
{
  const int i = blockIdx.x * blockDim.x + threadIdx.x;
  if (i < 24 * 768) {
    const int z = i / 768, d = i - z * 768;
    const float* src = (z < 8) ? bq : (z < 16) ? bk : bv;
    bqkv[i] = src[(z & 7) * 768 + d];
  }
}

// out[i] = sum_{kz<8} partials[kz][i] + bos[col]
__global__ void reduce8_kernel(const float* __restrict__ partials,
                               const float* __restrict__ bos,
                               float* __restrict__ out, int n4)
{
  const int i = blockIdx.x * blockDim.x + threadIdx.x;
  if (i < n4) {
    const long long stride4 = 4096LL * 768 / 4;
    float4 s = ((const float4*)partials)[i];
#pragma unroll
    for (int k2 = 1; k2 < 8; ++k2) {
      float4 p = ((const float4*)partials)[i + k2 * stride4];
      s.x += p.x; s.y += p.y; s.z += p.z; s.w += p.w;
    }
    const int col = (i * 4) % 768;
    const float4 b4 = *(const float4*)&bos[col];
    s.x += b4.x; s.y += b4.y; s.z += b4.z; s.w += b4.w;
    ((float4*)out)[i] = s;
  }
}

// in-place row softmax on bf16 [rows][1024]; one block (256 thr) per row
__global__ __launch_bounds__(256)
void softmax_kernel(unsigned short* __restrict__ S)
{
  const size_t row = blockIdx.x;
  unsigned short* p = S + row * 1024;
  const int t = threadIdx.x;

  s16x4 raw = *((const s16x4*)p + t);
  float v[4];
#pragma unroll
  for (int j = 0; j < 4; ++j) v[j] = bf2f((unsigned short)raw[j]);

  float mx = fmaxf(fmaxf(v[0], v[1]), fmaxf(v[2], v[3]));
#pragma unroll
  for (int o = 1; o < 64; o <<= 1) mx = fmaxf(mx, __shfl_xor(mx, o));

  __shared__ float red[8];
  if ((t & 63) == 0) red[t >> 6] = mx;
  __syncthreads();
  mx = fmaxf(fmaxf(red[0], red[1]), fmaxf(red[2], red[3]));

  float e[4], s = 0.f;
#pragma unroll
  for (int j = 0; j < 4; ++j) { e[j] = __expf(v[j] - mx); s += e[j]; }
#pragma unroll
  for (int o = 1; o < 64; o <<= 1) s += __shfl_xor(s, o);
  if ((t & 63) == 0) red[4 + (t >> 6)] = s;
  __syncthreads();
  s = red[4] + red[5] + red[6] + red[7];
  const float inv = 1.0f / s;

  s16x4 outv;
#pragma unroll
  for (int j = 0; j < 4; ++j) outv[j] = (short)f2bf(e[j] * inv);
  *((s16x4*)p + t) = outv;
}

// ---------------------------------------------------------------------------
extern "C" void kernel_launch(void* const* d_in, const int* in_sizes, int n_in,
                              void* d_out, int out_size, void* d_ws, size_t ws_size,
                              hipStream_t stream)
{
  (void)in_sizes; (void)n_in; (void)out_size;
  constexpr int Bb = 4, T = 1024, E = 768, D = 768, H = 8;
  constexpr int HD = H * D;                           // 6144
  constexpr long long TD = (long long)T * D;          // 786432
  constexpr long long TT = (long long)T * T;          // 1048576
  constexpr long long DE = (long long)D * E;          // 589824
  constexpr long long DT = (long long)D * T;          // 786432
  constexpr long long BHTD = (long long)Bb * H * T * D;  // 25165824
  constexpr long long HTD = (long long)H * TD;        // 6291456
  constexpr float SCALE = 0.03608439182435161f;       // 1/sqrt(E)

  const float* x  = (const float*)d_in[0];
  const float* wq = (const float*)d_in[1];
  const float* bq = (const float*)d_in[2];
  const float* wk = (const float*)d_in[3];
  const float* bk = (const float*)d_in[4];
  const float* wv = (const float*)d_in[5];
  const float* bv = (const float*)d_in[6];
  const float* wo = (const float*)d_in[7];
  const float* bo = (const float*)d_in[8];
  float* out = (float*)d_out;

  unsigned char* wsb = (unsigned char*)d_ws;
  const dim3 tb32(32, 8);

  // opt-in to 160 KiB dynamic LDS; fall back to 128x128 kernel if refused
  bool use256 = true;
  if (hipFuncSetAttribute(reinterpret_cast<const void*>(gemm256_kernel<false>),
                          hipFuncAttributeMaxDynamicSharedMemorySize, 163840)
      != hipSuccess) use256 = false;
  if (hipFuncSetAttribute(reinterpret_cast<const void*>(gemm256_kernel<true>),
                          hipFuncAttributeMaxDynamicSharedMemorySize, 163840)
      != hipSuccess) use256 = false;

  // ---- ALL32 tier peak footprint: 245,443,584 B ----
  if (ws_size >= 245443584ULL + 4096ULL) {
    unsigned short* woT   = (unsigned short*)(wsb + 0);            //  9,437,184
    float*          bos   = (float*)(wsb + 9437184);               //      3,072
    float*          bqkv  = (float*)(wsb + 9440256);               //     73,728
    unsigned short* vT    = (unsigned short*)(wsb + 9513984);      // 50,331,648
    unsigned short* qkv   = (unsigned short*)(wsb + 59845632);     // 3x 50,331,648
    unsigned short* q     = qkv;
    unsigned short* k     = qkv + BHTD;
    unsigned short* v     = qkv + 2 * BHTD;
    unsigned short* xb    = (unsigned short*)(wsb + 210840576);    //  6,291,456
    unsigned short* wqkvT = (unsigned short*)(wsb + 217132032);    // 28,311,552
    unsigned short* S     = v;          // overlays dead v+xb+wqkvT
    float*          part  = (float*)k;  // 8x12.6MB overlays dead k/v/S
    unsigned short* z2    = q;          // overlays dead q

    // --- prep ---
    convert_f32_bf16_kernel<<<3072, 256, 0, stream>>>(x, xb, Bb * T * E / 4);
    transpose_conv_kernel<<<dim3(24, 24, 8), tb32, 0, stream>>>(wq, wqkvT, E, D);
    transpose_conv_kernel<<<dim3(24, 24, 8), tb32, 0, stream>>>(wk, wqkvT + 8 * DE, E, D);
    transpose_conv_kernel<<<dim3(24, 24, 8), tb32, 0, stream>>>(wv, wqkvT + 16 * DE, E, D);
    transpose_conv_kernel<<<dim3(24, 192, 1), tb32, 0, stream>>>(wo, woT, HD, E);
    bosum_kernel<<<3, 256, 0, stream>>>(bo, bos);
    bconcat_kernel<<<72, 256, 0, stream>>>(bq, bk, bv, bqkv);

    if (use256) {
      // --- fused QKV: z = proj*8 + h ---
      gemm256_kernel<false><<<dim3(3, 16, 24), 512, 163840, stream>>>(
          xb, wqkvT, qkv, bqkv, E, E, E,
          0LL, DE, BHTD, TD, 3, HTD, 10, D, 768LL, 1.0f);
      transpose_bf16_kernel<<<dim3(24, 32, 32), tb32, 0, stream>>>(v, vT, T, D);
      // --- S = scale * q k^T ---
      gemm256_kernel<false><<<dim3(4, 4, 32), 512, 163840, stream>>>(
          q, k, S, nullptr, D, D, D,
          TD, TD, TT, 0LL, 0, 0LL, 30, T, 0LL, SCALE);
      softmax_kernel<<<Bb * H * T, 256, 0, stream>>>(S);
      // --- z2 = P v ---
      gemm256_kernel<false><<<dim3(3, 4, 32), 512, 163840, stream>>>(
          S, vT, z2, nullptr, T, T, T,
          TT, DT, (long long)T * HD, (long long)D, 3, 0LL, 30, HD, 0LL, 1.0f);
      // --- out-proj split-K=8 ---
      gemm256_kernel<true><<<dim3(3, 16, 8), 512, 163840, stream>>>(
          z2, woT, part, nullptr, 768, HD, HD,
          768LL, 768LL, 3145728LL, 0LL, 0, 0LL, 30, E, 0LL, 1.0f);
    } else {
      gemm_bt_kernel<false><<<dim3(6, 32, 24), 256, 0, stream>>>(
          xb, wqkvT, qkv, bqkv, E, E, E,
          0LL, DE, BHTD, TD, 3, HTD, 10, D, 768LL, 1.0f);
      transpose_bf16_kernel<<<dim3(24, 32, 32), tb32, 0, stream>>>(v, vT, T, D);
      gemm_bt_kernel<false><<<dim3(8, 8, 32), 256, 0, stream>>>(
          q, k, S, nullptr, D, D, D,
          TD, TD, TT, 0LL, 0, 0LL, 30, T, 0LL, SCALE);
      softmax_kernel<<<Bb * H * T, 256, 0, stream>>>(S);
      gemm_bt_kernel<false><<<dim3(6, 8, 32), 256, 0, stream>>>(
          S, vT, z2, nullptr, T, T, T,
          TT, DT, (long long)T * HD, (long long)D, 3, 0LL, 30, HD, 0LL, 1.0f);
      gemm_bt_kernel<true><<<dim3(6, 32, 8), 256, 0, stream>>>(
          z2, woT, part, nullptr, 768, HD, HD,
          768LL, 768LL, 3145728LL, 0LL, 0, 0LL, 30, E, 0LL, 1.0f);
    }
    reduce8_kernel<<<3072, 256, 0, stream>>>(part, bos, out, 4096 * 768 / 4);
    return;
  }

  // ---------------- fallback: proven chunked path (128x128 GEMM) ----------
  const size_t FIXED = 84937728ULL;
  const size_t PERCH = 8388608ULL;
  int CH = 8;
  while (CH > 1 && FIXED + (size_t)CH * PERCH > ws_size) CH >>= 1;

  size_t off = 0;
  auto carve = [&](size_t bytes) -> void* {
    void* p = wsb + off;
    off += (bytes + 255) & ~(size_t)255;
    return p;
  };
  unsigned short* xb  = (unsigned short*)carve((size_t)Bb * T * E * 2);
  unsigned short* wqT = (unsigned short*)carve((size_t)H * D * E * 2);
  unsigned short* wkT = (unsigned short*)carve((size_t)H * D * E * 2);
  unsigned short* wvT = (unsigned short*)carve((size_t)H * D * E * 2);
  float*          bos = (float*)carve(E * 4);
  unsigned short* z2  = (unsigned short*)carve((size_t)Bb * T * HD * 2);
  unsigned short* qc  = (unsigned short*)carve((size_t)CH * T * D * 2);
  unsigned short* kc  = (unsigned short*)carve((size_t)CH * T * D * 2);
  unsigned short* vc  = (unsigned short*)carve((size_t)CH * T * D * 2);
  unsigned short* vTc = (unsigned short*)carve((size_t)CH * D * T * 2);
  unsigned short* Sc  = (unsigned short*)carve((size_t)CH * T * T * 2);
  unsigned short* woT = wqT;  // wqT dead after chunk loop

  convert_f32_bf16_kernel<<<3072, 256, 0, stream>>>(x, xb, Bb * T * E / 4);
  transpose_conv_kernel<<<dim3(24, 24, 8), tb32, 0, stream>>>(wq, wqT, E, D);
  transpose_conv_kernel<<<dim3(24, 24, 8), tb32, 0, stream>>>(wk, wkT, E, D);
  transpose_conv_kernel<<<dim3(24, 24, 8), tb32, 0, stream>>>(wv, wvT, E, D);
  bosum_kernel<<<3, 256, 0, stream>>>(bo, bos);

  const int nchunks = (Bb * H) / CH;
  for (int c = 0; c < nchunks; ++c) {
    const int z0 = c * CH;
    const int b  = z0 >> 3;
    const int h0 = z0 & 7;
    const unsigned short* xbb = xb + (size_t)b * T * E;

    gemm_bt_kernel<false><<<dim3(6, 8, CH), 256, 0, stream>>>(
        xbb, wqT + (size_t)h0 * DE, qc, bq + (size_t)h0 * D, E, E, E,
        0LL, DE, TD, 0LL, 0, 0LL, 30, D, (long long)D, 1.0f);
    gemm_bt_kernel<false><<<dim3(6, 8, CH), 256, 0, stream>>>(
        xbb, wkT + (size_t)h0 * DE, kc, bk + (size_t)h0 * D, E, E, E,
        0LL, DE, TD, 0LL, 0, 0LL, 30, D, (long long)D, 1.0f);
    gemm_bt_kernel<false><<<dim3(6, 8, CH), 256, 0, stream>>>(
        xbb, wvT + (size_t)h0 * DE, vc, bv + (size_t)h0 * D, E, E, E,
        0LL, DE, TD, 0LL, 0, 0LL, 30, D, (long long)D, 1.0f);

    transpose_bf16_kernel<<<dim3(24, 32, CH), tb32, 0, stream>>>(vc, vTc, T, D);

    gemm_bt_kernel<false><<<dim3(8, 8, CH), 256, 0, stream>>>(
        qc, kc, Sc, nullptr, D, D, D,
        TD, TD, TT, 0LL, 0, 0LL, 30, T, 0LL, SCALE);

    softmax_kernel<<<CH * T, 256, 0, stream>>>(Sc);

    gemm_bt_kernel<false><<<dim3(6, 8, CH), 256, 0, stream>>>(
        Sc, vTc, z2 + (size_t)b * T * HD + (size_t)h0 * D, nullptr, T, T, T,
        TT, DT, (long long)D, 0LL, 0, 0LL, 30, HD, 0LL, 1.0f);
  }

  transpose_conv_kernel<<<dim3(24, 192, 1), tb32, 0, stream>>>(wo, woT, HD, E);
  gemm_bt_kernel<true><<<dim3(6, 32, 1), 256, 0, stream>>>(
      z2, woT, out, bos, HD, HD, HD,
      0LL, 0LL, 0LL, 0LL, 0, 0LL, 30, E, 0LL, 1.0f);
}

// Round 6
// 391.330 us; speedup vs baseline: 1.3097x; 1.2632x over previous
//
#include <hip/hip_runtime.h>
#include <hip/hip_bf16.h>

// ---------------------------------------------------------------------------
// MultiHeadAttention: B=4, T=1024, E=768, D=768, H=8, per-head full-width proj
// 128x128-tile 4-wave bf16 MFMA GEMM (m97 structure) + T2 LDS XOR-swizzle
// (pre-swizzled global source, swizzled ds_read) + T1 XCD swizzle.
// QKV kernel fuses V^T production in its epilogue (no transpose pass).
// Fallback (small ws): chunked path.
// ---------------------------------------------------------------------------

typedef __bf16 bf16x8 __attribute__((ext_vector_type(8)));
typedef float  f32x4  __attribute__((ext_vector_type(4)));
typedef short  s16x4  __attribute__((ext_vector_type(4)));

#define AS1 __attribute__((address_space(1)))
#define AS3 __attribute__((address_space(3)))

__device__ inline void gload_lds16(const void* g, void* l) {
  // async global->LDS, 16B/lane; LDS dest wave-uniform base + lane*16
  __builtin_amdgcn_global_load_lds((AS1 const void*)g, (AS3 void*)l, 16, 0, 0);
}

__device__ inline unsigned short f2bf(float f) {  // RNE f32 -> bf16 bits
  union { float f; unsigned u; } c; c.f = f;
  unsigned r = c.u + 0x7FFF + ((c.u >> 16) & 1);
  return (unsigned short)(r >> 16);
}
__device__ inline float bf2f(unsigned short u) {
  return __uint_as_float(((unsigned)u) << 16);
}

// XCD-aware bijective remap (T1); valid when total blocks % 8 == 0
__device__ inline void swizzle_bid(int& bx, int& by, int& bz) {
  const int gx = gridDim.x, gy = gridDim.y, gz = gridDim.z;
  const int n = gx * gy * gz;
  if ((n & 7) == 0) {
    int lin = (blockIdx.z * gy + blockIdx.y) * gx + blockIdx.x;
    lin = (lin & 7) * (n >> 3) + (lin >> 3);
    bz = lin / (gx * gy);
    const int rem = lin - bz * gx * gy;
    by = rem / gx;
    bx = rem - by * gx;
  } else {
    bx = blockIdx.x; by = blockIdx.y; bz = blockIdx.z;
  }
}

// ---------------------------------------------------------------------------
// GEMM: C = scale * A * Bt^T (+ bias[z*biasZ + n]); A:[M,lda] bf16, Bt:[N,ldb]
//   zoff  = (z>>zShift)*cZhi + (z & ((1<<zShift)-1))*cZlo
//   rowoff= (m>>rowShift)*cRowHi + (m & ((1<<rowShift)-1))*ldc
//   C[zoff + rowoff + n]
// T2 swizzle: LDS row = 64 bf16 = 8x16B units; LDS[row][u] holds
// global[row][u ^ (row&7)] (achieved by pre-swizzling the global source unit);
// reads XOR the unit back. Zero bank conflicts (verified R4/R5).
// If vtOut != nullptr and z >= 16: write C^T into vtOut[b][z-16][n][t]
// (fused V^T for QKV; packed 4x bf16 = 8B stores), skipping the normal write.
// Grid: (N/128, M/128, Z). 256 threads = 4 waves, each wave 64x64 output.
// ---------------------------------------------------------------------------
template<bool OUT_F32>
__global__ __launch_bounds__(256, 2)
void gemm_bt_kernel(const unsigned short* __restrict__ A,
                    const unsigned short* __restrict__ Bt,
                    void* __restrict__ Cout,
                    const float* __restrict__ bias,
                    int K, int lda, int ldb,
                    long long aZ, long long bZ,
                    long long cZhi, long long cZlo, int zShift,
                    long long cRowHi, int rowShift, int ldc,
                    long long biasZ, float scale,
                    unsigned short* __restrict__ vtOut)
{
  __shared__ unsigned short As[128 * 64];
  __shared__ unsigned short Bs[128 * 64];

  int ntile, mtile, z;
  swizzle_bid(ntile, mtile, z);

  const int tid  = threadIdx.x;
  const int wave = tid >> 6;
  const int lane = tid & 63;
  const int wm = wave >> 1, wn = wave & 1;

  const unsigned short* Ab = A  + (size_t)z * aZ + (size_t)mtile * 128 * lda;
  const unsigned short* Bb = Bt + (size_t)z * bZ + (size_t)ntile * 128 * ldb;

  const int rlane = lane >> 3;                    // 0..7 row within 8-row group
  const int su    = ((lane & 7) ^ rlane) * 8;     // pre-swizzled source unit

  // swizzled frag-read offsets: u_log = kk*4 + (lane>>4); u_phys = u_log^(lane&7)
  const int rsel  = lane & 15;
  const int usel  = lane & 7;
  const int ubase = lane >> 4;
  const int koff0 = ((ubase) ^ usel) * 8;         // kk=0
  const int koff1 = ((4 | ubase) ^ usel) * 8;     // kk=1

  f32x4 acc[4][4] = {};

  const int nkt = K >> 6;
  for (int kt = 0; kt < nkt; ++kt) {
    const int kbase = kt * 64;
    __syncthreads();
#pragma unroll
    for (int i = 0; i < 4; ++i) {
      const int r = wave * 32 + i * 8;            // wave-uniform base row
      gload_lds16(Ab + (size_t)(r + rlane) * lda + kbase + su, &As[r * 64]);
      gload_lds16(Bb + (size_t)(r + rlane) * ldb + kbase + su, &Bs[r * 64]);
    }
    __syncthreads();
#pragma unroll
    for (int kk = 0; kk < 2; ++kk) {
      const int koff = kk ? koff1 : koff0;
      bf16x8 af[4], bfr[4];
#pragma unroll
      for (int f = 0; f < 4; ++f) {
        af[f]  = *(const bf16x8*)&As[(wm * 64 + f * 16 + rsel) * 64 + koff];
        bfr[f] = *(const bf16x8*)&Bs[(wn * 64 + f * 16 + rsel) * 64 + koff];
      }
#pragma unroll
      for (int fm = 0; fm < 4; ++fm)
#pragma unroll
        for (int fn = 0; fn < 4; ++fn)
          acc[fm][fn] = __builtin_amdgcn_mfma_f32_16x16x32_bf16(af[fm], bfr[fn], acc[fm][fn], 0, 0, 0);
    }
  }

  // C/D frag layout: col = lane&15, row = (lane>>4)*4 + j  [m89]
  if (vtOut && z >= 16) {
    // fused V^T: vT[b][h][d][t], h = z-16; m = b*1024 + t, n = d
    const long long hoff = (long long)(z - 16) * 786432LL;   // D*T
#pragma unroll
    for (int fm = 0; fm < 4; ++fm) {
#pragma unroll
      for (int fn = 0; fn < 4; ++fn) {
        const int n  = ntile * 128 + wn * 64 + fn * 16 + (lane & 15);
        const int m0 = mtile * 128 + wm * 64 + fm * 16 + (lane >> 4) * 4;
        const int b  = m0 >> 10, t0 = m0 & 1023;
        const float bb = bias ? bias[(size_t)z * biasZ + n] : 0.f;
        s16x4 w;
#pragma unroll
        for (int j = 0; j < 4; ++j)
          w[j] = (short)f2bf(acc[fm][fn][j] * scale + bb);
        *(s16x4*)&vtOut[(size_t)b * 6291456 + hoff + (size_t)n * 1024 + t0] = w;
      }
    }
    return;
  }

  const long long zoff = (long long)(z >> zShift) * cZhi
                       + (long long)(z & ((1 << zShift) - 1)) * cZlo;
#pragma unroll
  for (int fm = 0; fm < 4; ++fm) {
#pragma unroll
    for (int j = 0; j < 4; ++j) {
      const int m = mtile * 128 + wm * 64 + fm * 16 + (lane >> 4) * 4 + j;
      const long long rowoff = (long long)(m >> rowShift) * cRowHi
                             + (long long)(m & ((1 << rowShift) - 1)) * ldc;
#pragma unroll
      for (int fn = 0; fn < 4; ++fn) {
        const int n = ntile * 128 + wn * 64 + fn * 16 + (lane & 15);
        float v = acc[fm][fn][j] * scale;
        if (bias) v += bias[(size_t)z * biasZ + n];
        const long long cidx = zoff + rowoff + n;
        if (OUT_F32) ((float*)Cout)[cidx] = v;
        else ((unsigned short*)Cout)[cidx] = f2bf(v);
      }
    }
  }
}

// fp32 [Z][R][C] -> bf16 [Z][C][R] tile transpose+convert
__global__ void transpose_conv_kernel(const float* __restrict__ in,
                                      unsigned short* __restrict__ out,
                                      int R, int C)
{
  __shared__ float tile[32][33];
  const size_t zo = (size_t)blockIdx.z * R * C;
  const int c0 = blockIdx.x * 32, r0 = blockIdx.y * 32;
  const int tx = threadIdx.x, ty = threadIdx.y;
#pragma unroll
  for (int i = ty; i < 32; i += 8)
    tile[i][tx] = in[zo + (size_t)(r0 + i) * C + c0 + tx];
  __syncthreads();
#pragma unroll
  for (int i = ty; i < 32; i += 8)
    out[zo + (size_t)(c0 + i) * R + r0 + tx] = f2bf(tile[tx][i]);
}

// bf16 [Z][R][C] -> bf16 [Z][C][R]  (fallback path only)
__global__ void transpose_bf16_kernel(const unsigned short* __restrict__ in,
                                      unsigned short* __restrict__ out,
                                      int R, int C)
{
  __shared__ unsigned short tile[32][33];
  const size_t zo = (size_t)blockIdx.z * R * C;
  const int c0 = blockIdx.x * 32, r0 = blockIdx.y * 32;
  const int tx = threadIdx.x, ty = threadIdx.y;
#pragma unroll
  for (int i = ty; i < 32; i += 8)
    tile[i][tx] = in[zo + (size_t)(r0 + i) * C + c0 + tx];
  __syncthreads();
#pragma unroll
  for (int i = ty; i < 32; i += 8)
    out[zo + (size_t)(c0 + i) * R + r0 + tx] = tile[tx][i];
}

__global__ void convert_f32_bf16_kernel(const float* __restrict__ in,
                                        unsigned short* __restrict__ out, int n4)
{
  const int i = blockIdx.x * blockDim.x + threadIdx.x;
  if (i < n4) {
    const float4 f = ((const float4*)in)[i];
    s16x4 o;
    o[0] = (short)f2bf(f.x); o[1] = (short)f2bf(f.y);
    o[2] = (short)f2bf(f.z); o[3] = (short)f2bf(f.w);
    ((s16x4*)out)[i] = o;
  }
}

__global__ void bosum_kernel(const float* __restrict__ bo, float* __restrict__ bos)
{
  const int e = blockIdx.x * blockDim.x + threadIdx.x;
  if (e < 768) {
    float s = 0.f;
#pragma unroll
    for (int h = 0; h < 8; ++h) s += bo[h * 768 + e];
    bos[e] = s;
  }
}

// concat bq,bk,bv -> bqkv[24][768] (z = proj*8 + h)
__global__ void bconcat_kernel(const float* __restrict__ bq,
                               const float* __restrict__ bk,
                               const float* __restrict__ bv,
                               float* __restrict__ bqkv)
{
  const int i = blockIdx.x * blockDim.x + threadIdx.x;
  if (i < 24 * 768) {
    const int z = i / 768, d = i - z * 768;
    const float* src = (z < 8) ? bq : (z < 16) ? bk : bv;
    bqkv[i] = src[(z & 7) * 768 + d];
  }
}

// out[i] = sum_{kz<8} partials[kz][i] + bos[col]
__global__ void reduce8_kernel(const float* __restrict__ partials,
                               const float* __restrict__ bos,
                               float* __restrict__ out, int n4)
{
  const int i = blockIdx.x * blockDim.x + threadIdx.x;
  if (i < n4) {
    const long long stride4 = 4096LL * 768 / 4;
    float4 s = ((const float4*)partials)[i];
#pragma unroll
    for (int k2 = 1; k2 < 8; ++k2) {
      float4 p = ((const float4*)partials)[i + k2 * stride4];
      s.x += p.x; s.y += p.y; s.z += p.z; s.w += p.w;
    }
    const int col = (i * 4) % 768;
    const float4 b4 = *(const float4*)&bos[col];
    s.x += b4.x; s.y += b4.y; s.z += b4.z; s.w += b4.w;
    ((float4*)out)[i] = s;
  }
}

// in-place row softmax on bf16 [rows][1024]; one block (256 thr) per row
__global__ __launch_bounds__(256)
void softmax_kernel(unsigned short* __restrict__ S)
{
  const size_t row = blockIdx.x;
  unsigned short* p = S + row * 1024;
  const int t = threadIdx.x;

  s16x4 raw = *((const s16x4*)p + t);
  float v[4];
#pragma unroll
  for (int j = 0; j < 4; ++j) v[j] = bf2f((unsigned short)raw[j]);

  float mx = fmaxf(fmaxf(v[0], v[1]), fmaxf(v[2], v[3]));
#pragma unroll
  for (int o = 1; o < 64; o <<= 1) mx = fmaxf(mx, __shfl_xor(mx, o));

  __shared__ float red[8];
  if ((t & 63) == 0) red[t >> 6] = mx;
  __syncthreads();
  mx = fmaxf(fmaxf(red[0], red[1]), fmaxf(red[2], red[3]));

  float e[4], s = 0.f;
#pragma unroll
  for (int j = 0; j < 4; ++j) { e[j] = __expf(v[j] - mx); s += e[j]; }
#pragma unroll
  for (int o = 1; o < 64; o <<= 1) s += __shfl_xor(s, o);
  if ((t & 63) == 0) red[4 + (t >> 6)] = s;
  __syncthreads();
  s = red[4] + red[5] + red[6] + red[7];
  const float inv = 1.0f / s;

  s16x4 outv;
#pragma unroll
  for (int j = 0; j < 4; ++j) outv[j] = (short)f2bf(e[j] * inv);
  *((s16x4*)p + t) = outv;
}

// ---------------------------------------------------------------------------
extern "C" void kernel_launch(void* const* d_in, const int* in_sizes, int n_in,
                              void* d_out, int out_size, void* d_ws, size_t ws_size,
                              hipStream_t stream)
{
  (void)in_sizes; (void)n_in; (void)out_size;
  constexpr int Bb = 4, T = 1024, E = 768, D = 768, H = 8;
  constexpr int HD = H * D;                           // 6144
  constexpr long long TD = (long long)T * D;          // 786432
  constexpr long long TT = (long long)T * T;          // 1048576
  constexpr long long DE = (long long)D * E;          // 589824
  constexpr long long DT = (long long)D * T;          // 786432
  constexpr long long BHTD = (long long)Bb * H * T * D;  // 25165824
  constexpr long long HTD = (long long)H * TD;        // 6291456
  constexpr float SCALE = 0.03608439182435161f;       // 1/sqrt(E)

  const float* x  = (const float*)d_in[0];
  const float* wq = (const float*)d_in[1];
  const float* bq = (const float*)d_in[2];
  const float* wk = (const float*)d_in[3];
  const float* bk = (const float*)d_in[4];
  const float* wv = (const float*)d_in[5];
  const float* bv = (const float*)d_in[6];
  const float* wo = (const float*)d_in[7];
  const float* bo = (const float*)d_in[8];
  float* out = (float*)d_out;

  unsigned char* wsb = (unsigned char*)d_ws;
  const dim3 tb32(32, 8);

  // ---- ALL32 tier peak footprint: 245,443,584 B ----
  if (ws_size >= 245443584ULL + 4096ULL) {
    unsigned short* woT   = (unsigned short*)(wsb + 0);            //  9,437,184
    float*          bos   = (float*)(wsb + 9437184);               //      3,072
    float*          bqkv  = (float*)(wsb + 9440256);               //     73,728
    unsigned short* vT    = (unsigned short*)(wsb + 9513984);      // 50,331,648
    unsigned short* qkv   = (unsigned short*)(wsb + 59845632);     // 3x 50,331,648
    unsigned short* q     = qkv;
    unsigned short* k     = qkv + BHTD;
    unsigned short* v     = qkv + 2 * BHTD;                        // unwritten
    unsigned short* xb    = (unsigned short*)(wsb + 210840576);    //  6,291,456
    unsigned short* wqkvT = (unsigned short*)(wsb + 217132032);    // 28,311,552
    unsigned short* S     = v;          // overlays v region (+xb+wqkvT)
    float*          part  = (float*)k;  // 8x12.6MB overlays dead k + S region
    unsigned short* z2    = q;          // overlays dead q

    // --- prep ---
    convert_f32_bf16_kernel<<<3072, 256, 0, stream>>>(x, xb, Bb * T * E / 4);
    transpose_conv_kernel<<<dim3(24, 24, 8), tb32, 0, stream>>>(wq, wqkvT, E, D);
    transpose_conv_kernel<<<dim3(24, 24, 8), tb32, 0, stream>>>(wk, wqkvT + 8 * DE, E, D);
    transpose_conv_kernel<<<dim3(24, 24, 8), tb32, 0, stream>>>(wv, wqkvT + 16 * DE, E, D);
    transpose_conv_kernel<<<dim3(24, 192, 1), tb32, 0, stream>>>(wo, woT, HD, E);
    bosum_kernel<<<3, 256, 0, stream>>>(bo, bos);
    bconcat_kernel<<<72, 256, 0, stream>>>(bq, bk, bv, bqkv);

    // --- fused QKV: z = proj*8 + h; z>=16 (V) writes vT[b][h][d][t] directly
    gemm_bt_kernel<false><<<dim3(6, 32, 24), 256, 0, stream>>>(
        xb, wqkvT, qkv, bqkv, E, E, E,
        0LL, DE, BHTD, TD, 3, HTD, 10, D, 768LL, 1.0f, vT);

    // --- S = scale * q k^T  [BH,T,T] over all 32 (b,h) ---
    gemm_bt_kernel<false><<<dim3(8, 8, 32), 256, 0, stream>>>(
        q, k, S, nullptr, D, D, D,
        TD, TD, TT, 0LL, 0, 0LL, 30, T, 0LL, SCALE, nullptr);

    // --- softmax all rows ---
    softmax_kernel<<<Bb * H * T, 256, 0, stream>>>(S);

    // --- z2[b,t,h*D+n] = P v : z = b*8+h ---
    gemm_bt_kernel<false><<<dim3(6, 8, 32), 256, 0, stream>>>(
        S, vT, z2, nullptr, T, T, T,
        TT, DT, (long long)T * HD, (long long)D, 3, 0LL, 30, HD, 0LL, 1.0f, nullptr);

    // --- out-proj split-K=8: partials[kz][4096][768] fp32 ---
    gemm_bt_kernel<true><<<dim3(6, 32, 8), 256, 0, stream>>>(
        z2, woT, part, nullptr, 768, HD, HD,
        768LL, 768LL, 3145728LL, 0LL, 0, 0LL, 30, E, 0LL, 1.0f, nullptr);
    reduce8_kernel<<<3072, 256, 0, stream>>>(part, bos, out, 4096 * 768 / 4);
    return;
  }

  // ---------------- fallback: proven chunked path ----------------
  const size_t FIXED = 84937728ULL;
  const size_t PERCH = 8388608ULL;
  int CH = 8;
  while (CH > 1 && FIXED + (size_t)CH * PERCH > ws_size) CH >>= 1;

  size_t off = 0;
  auto carve = [&](size_t bytes) -> void* {
    void* p = wsb + off;
    off += (bytes + 255) & ~(size_t)255;
    return p;
  };
  unsigned short* xb  = (unsigned short*)carve((size_t)Bb * T * E * 2);
  unsigned short* wqT = (unsigned short*)carve((size_t)H * D * E * 2);
  unsigned short* wkT = (unsigned short*)carve((size_t)H * D * E * 2);
  unsigned short* wvT = (unsigned short*)carve((size_t)H * D * E * 2);
  float*          bos = (float*)carve(E * 4);
  unsigned short* z2  = (unsigned short*)carve((size_t)Bb * T * HD * 2);
  unsigned short* qc  = (unsigned short*)carve((size_t)CH * T * D * 2);
  unsigned short* kc  = (unsigned short*)carve((size_t)CH * T * D * 2);
  unsigned short* vc  = (unsigned short*)carve((size_t)CH * T * D * 2);
  unsigned short* vTc = (unsigned short*)carve((size_t)CH * D * T * 2);
  unsigned short* Sc  = (unsigned short*)carve((size_t)CH * T * T * 2);
  unsigned short* woT = wqT;  // wqT dead after chunk loop

  convert_f32_bf16_kernel<<<3072, 256, 0, stream>>>(x, xb, Bb * T * E / 4);
  transpose_conv_kernel<<<dim3(24, 24, 8), tb32, 0, stream>>>(wq, wqT, E, D);
  transpose_conv_kernel<<<dim3(24, 24, 8), tb32, 0, stream>>>(wk, wkT, E, D);
  transpose_conv_kernel<<<dim3(24, 24, 8), tb32, 0, stream>>>(wv, wvT, E, D);
  bosum_kernel<<<3, 256, 0, stream>>>(bo, bos);

  const int nchunks = (Bb * H) / CH;
  for (int c = 0; c < nchunks; ++c) {
    const int z0 = c * CH;
    const int b  = z0 >> 3;
    const int h0 = z0 & 7;
    const unsigned short* xbb = xb + (size_t)b * T * E;

    gemm_bt_kernel<false><<<dim3(6, 8, CH), 256, 0, stream>>>(
        xbb, wqT + (size_t)h0 * DE, qc, bq + (size_t)h0 * D, E, E, E,
        0LL, DE, TD, 0LL, 0, 0LL, 30, D, (long long)D, 1.0f, nullptr);
    gemm_bt_kernel<false><<<dim3(6, 8, CH), 256, 0, stream>>>(
        xbb, wkT + (size_t)h0 * DE, kc, bk + (size_t)h0 * D, E, E, E,
        0LL, DE, TD, 0LL, 0, 0LL, 30, D, (long long)D, 1.0f, nullptr);
    gemm_bt_kernel<false><<<dim3(6, 8, CH), 256, 0, stream>>>(
        xbb, wvT + (size_t)h0 * DE, vc, bv + (size_t)h0 * D, E, E, E,
        0LL, DE, TD, 0LL, 0, 0LL, 30, D, (long long)D, 1.0f, nullptr);

    transpose_bf16_kernel<<<dim3(24, 32, CH), tb32, 0, stream>>>(vc, vTc, T, D);

    gemm_bt_kernel<false><<<dim3(8, 8, CH), 256, 0, stream>>>(
        qc, kc, Sc, nullptr, D, D, D,
        TD, TD, TT, 0LL, 0, 0LL, 30, T, 0LL, SCALE, nullptr);

    softmax_kernel<<<CH * T, 256, 0, stream>>>(Sc);

    gemm_bt_kernel<false><<<dim3(6, 8, CH), 256, 0, stream>>>(
        Sc, vTc, z2 + (size_t)b * T * HD + (size_t)h0 * D, nullptr, T, T, T,
        TT, DT, (long long)D, 0LL, 0, 0LL, 30, HD, 0LL, 1.0f, nullptr);
  }

  transpose_conv_kernel<<<dim3(24, 192, 1), tb32, 0, stream>>>(wo, woT, HD, E);
  gemm_bt_kernel<true><<<dim3(6, 32, 1), 256, 0, stream>>>(
      z2, woT, out, bos, HD, HD, HD,
      0LL, 0LL, 0LL, 0LL, 0, 0LL, 30, E, 0LL, 1.0f, nullptr);
}

// Round 7
// 356.317 us; speedup vs baseline: 1.4383x; 1.0983x over previous
//
#include <hip/hip_runtime.h>
#include <hip/hip_bf16.h>

// ---------------------------------------------------------------------------
// MultiHeadAttention: B=4, T=1024, E=768, D=768, H=8, per-head full-width proj
// 128x128-tile 4-wave bf16 MFMA GEMM + T2 LDS XOR-swizzle + T1 XCD swizzle.
// Fusions: QKV epilogue writes V^T directly; S epilogue does exp()+row-partial
// sums (softmax denominator factored out of PV: PV epilogue scales by 1/den);
// out-proj split-K=4 + reduce4. No separate softmax pass.
// Fallback (small ws): proven chunked path.
// ---------------------------------------------------------------------------

typedef __bf16 bf16x8 __attribute__((ext_vector_type(8)));
typedef float  f32x4  __attribute__((ext_vector_type(4)));
typedef short  s16x4  __attribute__((ext_vector_type(4)));

#define AS1 __attribute__((address_space(1)))
#define AS3 __attribute__((address_space(3)))

__device__ inline void gload_lds16(const void* g, void* l) {
  // async global->LDS, 16B/lane; LDS dest wave-uniform base + lane*16
  __builtin_amdgcn_global_load_lds((AS1 const void*)g, (AS3 void*)l, 16, 0, 0);
}

__device__ inline unsigned short f2bf(float f) {  // RNE f32 -> bf16 bits
  union { float f; unsigned u; } c; c.f = f;
  unsigned r = c.u + 0x7FFF + ((c.u >> 16) & 1);
  return (unsigned short)(r >> 16);
}
__device__ inline float bf2f(unsigned short u) {
  return __uint_as_float(((unsigned)u) << 16);
}

// XCD-aware bijective remap (T1); valid when total blocks % 8 == 0
__device__ inline void swizzle_bid(int& bx, int& by, int& bz) {
  const int gx = gridDim.x, gy = gridDim.y, gz = gridDim.z;
  const int n = gx * gy * gz;
  if ((n & 7) == 0) {
    int lin = (blockIdx.z * gy + blockIdx.y) * gx + blockIdx.x;
    lin = (lin & 7) * (n >> 3) + (lin >> 3);
    bz = lin / (gx * gy);
    const int rem = lin - bz * gx * gy;
    by = rem / gx;
    bx = rem - by * gx;
  } else {
    bx = blockIdx.x; by = blockIdx.y; bz = blockIdx.z;
  }
}

// ---------------------------------------------------------------------------
// GEMM: C = scale * A * Bt^T (+ bias[z*biasZ + n]); A:[M,lda] bf16, Bt:[N,ldb]
//   zoff  = (z>>zShift)*cZhi + (z & ((1<<zShift)-1))*cZlo
//   rowoff= (m>>rowShift)*cRowHi + (m & ((1<<rowShift)-1))*ldc
//   C[zoff + rowoff + n]
// T2 swizzle: LDS[row][u16B] holds global[row][u ^ (row&7)] (pre-swizzled
// source, linear gload_lds dest); reads XOR the unit back. 0 conflicts (R4-R6).
// Epilogue modes:
//  - vtOut && z>=16  : write C^T into vtOut[b][z-16][n][t] (fused V^T)
//  - rowsumOut       : e=exp(v*scale); write e (bf16) + per-row partial sums
//                      rowsumOut[(z*8+ntile)*1024 + m]   (softmax fused)
//  - rowScale        : v *= rowScale[z*1024+m] before store (PV normalization)
// Grid: (N/128, M/128, Z). 256 threads = 4 waves, each wave 64x64 output.
// ---------------------------------------------------------------------------
template<bool OUT_F32>
__global__ __launch_bounds__(256, 2)
void gemm_bt_kernel(const unsigned short* __restrict__ A,
                    const unsigned short* __restrict__ Bt,
                    void* __restrict__ Cout,
                    const float* __restrict__ bias,
                    int K, int lda, int ldb,
                    long long aZ, long long bZ,
                    long long cZhi, long long cZlo, int zShift,
                    long long cRowHi, int rowShift, int ldc,
                    long long biasZ, float scale,
                    unsigned short* __restrict__ vtOut,
                    float* __restrict__ rowsumOut,
                    const float* __restrict__ rowScale)
{
  __shared__ unsigned short As[128 * 64];
  __shared__ unsigned short Bs[128 * 64];

  int ntile, mtile, z;
  swizzle_bid(ntile, mtile, z);

  const int tid  = threadIdx.x;
  const int wave = tid >> 6;
  const int lane = tid & 63;
  const int wm = wave >> 1, wn = wave & 1;

  const unsigned short* Ab = A  + (size_t)z * aZ + (size_t)mtile * 128 * lda;
  const unsigned short* Bb = Bt + (size_t)z * bZ + (size_t)ntile * 128 * ldb;

  const int rlane = lane >> 3;                    // 0..7 row within 8-row group
  const int su    = ((lane & 7) ^ rlane) * 8;     // pre-swizzled source unit

  // swizzled frag-read offsets: u_log = kk*4 + (lane>>4); u_phys = u_log^(lane&7)
  const int rsel  = lane & 15;
  const int usel  = lane & 7;
  const int ubase = lane >> 4;
  const int koff0 = ((ubase) ^ usel) * 8;         // kk=0
  const int koff1 = ((4 | ubase) ^ usel) * 8;     // kk=1

  f32x4 acc[4][4] = {};

  const int nkt = K >> 6;
  for (int kt = 0; kt < nkt; ++kt) {
    const int kbase = kt * 64;
    __syncthreads();
#pragma unroll
    for (int i = 0; i < 4; ++i) {
      const int r = wave * 32 + i * 8;            // wave-uniform base row
      gload_lds16(Ab + (size_t)(r + rlane) * lda + kbase + su, &As[r * 64]);
      gload_lds16(Bb + (size_t)(r + rlane) * ldb + kbase + su, &Bs[r * 64]);
    }
    __syncthreads();
#pragma unroll
    for (int kk = 0; kk < 2; ++kk) {
      const int koff = kk ? koff1 : koff0;
      bf16x8 af[4], bfr[4];
#pragma unroll
      for (int f = 0; f < 4; ++f) {
        af[f]  = *(const bf16x8*)&As[(wm * 64 + f * 16 + rsel) * 64 + koff];
        bfr[f] = *(const bf16x8*)&Bs[(wn * 64 + f * 16 + rsel) * 64 + koff];
      }
#pragma unroll
      for (int fm = 0; fm < 4; ++fm)
#pragma unroll
        for (int fn = 0; fn < 4; ++fn)
          acc[fm][fn] = __builtin_amdgcn_mfma_f32_16x16x32_bf16(af[fm], bfr[fn], acc[fm][fn], 0, 0, 0);
    }
  }

  // C/D frag layout: col = lane&15, row = (lane>>4)*4 + j  [m89]
  if (vtOut && z >= 16) {
    // fused V^T: vT[b][h][d][t], h = z-16; m = b*1024 + t, n = d
    const long long hoff = (long long)(z - 16) * 786432LL;   // D*T
#pragma unroll
    for (int fm = 0; fm < 4; ++fm) {
#pragma unroll
      for (int fn = 0; fn < 4; ++fn) {
        const int n  = ntile * 128 + wn * 64 + fn * 16 + (lane & 15);
        const int m0 = mtile * 128 + wm * 64 + fm * 16 + (lane >> 4) * 4;
        const int b  = m0 >> 10, t0 = m0 & 1023;
        const float bb = bias ? bias[(size_t)z * biasZ + n] : 0.f;
        s16x4 w;
#pragma unroll
        for (int j = 0; j < 4; ++j)
          w[j] = (short)f2bf(acc[fm][fn][j] * scale + bb);
        *(s16x4*)&vtOut[(size_t)b * 6291456 + hoff + (size_t)n * 1024 + t0] = w;
      }
    }
    return;
  }

  const long long zoff = (long long)(z >> zShift) * cZhi
                       + (long long)(z & ((1 << zShift) - 1)) * cZlo;

  if (rowsumOut) {
    // fused exp + per-row partial sums (softmax numerator + denominator parts)
    __syncthreads();                       // all waves done reading As/Bs
    float* redsum = (float*)As;            // [128][2] floats, aliases As
#pragma unroll
    for (int fm = 0; fm < 4; ++fm) {
#pragma unroll
      for (int j = 0; j < 4; ++j) {
        const int m = mtile * 128 + wm * 64 + fm * 16 + (lane >> 4) * 4 + j;
        const long long rowoff = (long long)(m >> rowShift) * cRowHi
                               + (long long)(m & ((1 << rowShift) - 1)) * ldc;
        float part = 0.f;
#pragma unroll
        for (int fn = 0; fn < 4; ++fn) {
          const int n = ntile * 128 + wn * 64 + fn * 16 + (lane & 15);
          const float e = __expf(acc[fm][fn][j] * scale);
          part += e;
          ((unsigned short*)Cout)[zoff + rowoff + n] = f2bf(e);
        }
#pragma unroll
        for (int o = 1; o < 16; o <<= 1) part += __shfl_xor(part, o);
        if ((lane & 15) == 0)
          redsum[(wm * 64 + fm * 16 + (lane >> 4) * 4 + j) * 2 + wn] = part;
      }
    }
    __syncthreads();
    if (tid < 128) {
      const int m = mtile * 128 + tid;
      rowsumOut[((long long)z * 8 + ntile) * 1024 + m] =
          redsum[tid * 2 + 0] + redsum[tid * 2 + 1];
    }
    return;
  }

#pragma unroll
  for (int fm = 0; fm < 4; ++fm) {
#pragma unroll
    for (int j = 0; j < 4; ++j) {
      const int m = mtile * 128 + wm * 64 + fm * 16 + (lane >> 4) * 4 + j;
      const long long rowoff = (long long)(m >> rowShift) * cRowHi
                             + (long long)(m & ((1 << rowShift) - 1)) * ldc;
      const float rsc = rowScale ? rowScale[(size_t)z * 1024 + (m & 1023)] : 1.0f;
#pragma unroll
      for (int fn = 0; fn < 4; ++fn) {
        const int n = ntile * 128 + wn * 64 + fn * 16 + (lane & 15);
        float v = acc[fm][fn][j] * scale;
        if (bias) v += bias[(size_t)z * biasZ + n];
        v *= rsc;
        const long long cidx = zoff + rowoff + n;
        if (OUT_F32) ((float*)Cout)[cidx] = v;
        else ((unsigned short*)Cout)[cidx] = f2bf(v);
      }
    }
  }
}

// ---------------------------------------------------------------------------
// merged weight prep: z<24 -> wq/wk/wv head (z&7) transposed into wqkvT[z],
// z>=24 -> wo head (z-24) transposed into woT columns [h*768..h*768+768)
// all slices are 768x768 fp32 -> bf16 transpose
// ---------------------------------------------------------------------------
__global__ void prep_weights_kernel(const float* __restrict__ wq,
                                    const float* __restrict__ wk,
                                    const float* __restrict__ wv,
                                    const float* __restrict__ wo,
                                    unsigned short* __restrict__ wqkvT,
                                    unsigned short* __restrict__ woT)
{
  __shared__ float tile[32][33];
  const int z = blockIdx.z;
  const float* in;
  unsigned short* outp;
  int outLD;
  if (z < 24) {
    const float* base = (z < 8) ? wq : (z < 16) ? wk : wv;
    in   = base + (size_t)(z & 7) * 589824;
    outp = wqkvT + (size_t)z * 589824;
    outLD = 768;
  } else {
    in   = wo + (size_t)(z - 24) * 589824;
    outp = woT + (size_t)(z - 24) * 768;
    outLD = 6144;
  }
  const int c0 = blockIdx.x * 32, r0 = blockIdx.y * 32;
  const int tx = threadIdx.x, ty = threadIdx.y;
#pragma unroll
  for (int i = ty; i < 32; i += 8)
    tile[i][tx] = in[(size_t)(r0 + i) * 768 + c0 + tx];
  __syncthreads();
#pragma unroll
  for (int i = ty; i < 32; i += 8)
    outp[(size_t)(c0 + i) * outLD + r0 + tx] = f2bf(tile[tx][i]);
}

// fp32 [Z][R][C] -> bf16 [Z][C][R] tile transpose+convert (fallback path)
__global__ void transpose_conv_kernel(const float* __restrict__ in,
                                      unsigned short* __restrict__ out,
                                      int R, int C)
{
  __shared__ float tile[32][33];
  const size_t zo = (size_t)blockIdx.z * R * C;
  const int c0 = blockIdx.x * 32, r0 = blockIdx.y * 32;
  const int tx = threadIdx.x, ty = threadIdx.y;
#pragma unroll
  for (int i = ty; i < 32; i += 8)
    tile[i][tx] = in[zo + (size_t)(r0 + i) * C + c0 + tx];
  __syncthreads();
#pragma unroll
  for (int i = ty; i < 32; i += 8)
    out[zo + (size_t)(c0 + i) * R + r0 + tx] = f2bf(tile[tx][i]);
}

// bf16 [Z][R][C] -> bf16 [Z][C][R]  (fallback path only)
__global__ void transpose_bf16_kernel(const unsigned short* __restrict__ in,
                                      unsigned short* __restrict__ out,
                                      int R, int C)
{
  __shared__ unsigned short tile[32][33];
  const size_t zo = (size_t)blockIdx.z * R * C;
  const int c0 = blockIdx.x * 32, r0 = blockIdx.y * 32;
  const int tx = threadIdx.x, ty = threadIdx.y;
#pragma unroll
  for (int i = ty; i < 32; i += 8)
    tile[i][tx] = in[zo + (size_t)(r0 + i) * C + c0 + tx];
  __syncthreads();
#pragma unroll
  for (int i = ty; i < 32; i += 8)
    out[zo + (size_t)(c0 + i) * R + r0 + tx] = tile[tx][i];
}

__global__ void convert_f32_bf16_kernel(const float* __restrict__ in,
                                        unsigned short* __restrict__ out, int n4)
{
  const int i = blockIdx.x * blockDim.x + threadIdx.x;
  if (i < n4) {
    const float4 f = ((const float4*)in)[i];
    s16x4 o;
    o[0] = (short)f2bf(f.x); o[1] = (short)f2bf(f.y);
    o[2] = (short)f2bf(f.z); o[3] = (short)f2bf(f.w);
    ((s16x4*)out)[i] = o;
  }
}

__global__ void bosum_kernel(const float* __restrict__ bo, float* __restrict__ bos)
{
  const int e = blockIdx.x * blockDim.x + threadIdx.x;
  if (e < 768) {
    float s = 0.f;
#pragma unroll
    for (int h = 0; h < 8; ++h) s += bo[h * 768 + e];
    bos[e] = s;
  }
}

// concat bq,bk,bv -> bqkv[24][768] (z = proj*8 + h)
__global__ void bconcat_kernel(const float* __restrict__ bq,
                               const float* __restrict__ bk,
                               const float* __restrict__ bv,
                               float* __restrict__ bqkv)
{
  const int i = blockIdx.x * blockDim.x + threadIdx.x;
  if (i < 24 * 768) {
    const int z = i / 768, d = i - z * 768;
    const float* src = (z < 8) ? bq : (z < 16) ? bk : bv;
    bqkv[i] = src[(z & 7) * 768 + d];
  }
}

// invden[z*1024+t] = 1 / sum_{nt<8} rowsum[(z*8+nt)*1024 + t]
__global__ void invden_kernel(const float* __restrict__ rowsum,
                              float* __restrict__ invden)
{
  const int i = blockIdx.x * blockDim.x + threadIdx.x;
  if (i < 32 * 1024) {
    const int z = i >> 10, t = i & 1023;
    const float* p = rowsum + (size_t)z * 8192 + t;
    float s = 0.f;
#pragma unroll
    for (int nt = 0; nt < 8; ++nt) s += p[nt * 1024];
    invden[i] = 1.0f / s;
  }
}

// out[i] = sum_{kz<4} partials[kz][i] + bos[col]
__global__ void reduce4_kernel(const float* __restrict__ partials,
                               const float* __restrict__ bos,
                               float* __restrict__ out, int n4)
{
  const int i = blockIdx.x * blockDim.x + threadIdx.x;
  if (i < n4) {
    const long long stride4 = 4096LL * 768 / 4;
    float4 a = ((const float4*)partials)[i];
    float4 b = ((const float4*)partials)[i + stride4];
    float4 c = ((const float4*)partials)[i + 2 * stride4];
    float4 d = ((const float4*)partials)[i + 3 * stride4];
    const int col = (i * 4) % 768;
    const float4 b4 = *(const float4*)&bos[col];
    float4 r;
    r.x = a.x + b.x + c.x + d.x + b4.x;
    r.y = a.y + b.y + c.y + d.y + b4.y;
    r.z = a.z + b.z + c.z + d.z + b4.z;
    r.w = a.w + b.w + c.w + d.w + b4.w;
    ((float4*)out)[i] = r;
  }
}

// in-place row softmax on bf16 [rows][1024] (fallback path only)
__global__ __launch_bounds__(256)
void softmax_kernel(unsigned short* __restrict__ S)
{
  const size_t row = blockIdx.x;
  unsigned short* p = S + row * 1024;
  const int t = threadIdx.x;

  s16x4 raw = *((const s16x4*)p + t);
  float v[4];
#pragma unroll
  for (int j = 0; j < 4; ++j) v[j] = bf2f((unsigned short)raw[j]);

  float mx = fmaxf(fmaxf(v[0], v[1]), fmaxf(v[2], v[3]));
#pragma unroll
  for (int o = 1; o < 64; o <<= 1) mx = fmaxf(mx, __shfl_xor(mx, o));

  __shared__ float red[8];
  if ((t & 63) == 0) red[t >> 6] = mx;
  __syncthreads();
  mx = fmaxf(fmaxf(red[0], red[1]), fmaxf(red[2], red[3]));

  float e[4], s = 0.f;
#pragma unroll
  for (int j = 0; j < 4; ++j) { e[j] = __expf(v[j] - mx); s += e[j]; }
#pragma unroll
  for (int o = 1; o < 64; o <<= 1) s += __shfl_xor(s, o);
  if ((t & 63) == 0) red[4 + (t >> 6)] = s;
  __syncthreads();
  s = red[4] + red[5] + red[6] + red[7];
  const float inv = 1.0f / s;

  s16x4 outv;
#pragma unroll
  for (int j = 0; j < 4; ++j) outv[j] = (short)f2bf(e[j] * inv);
  *((s16x4*)p + t) = outv;
}

// ---------------------------------------------------------------------------
extern "C" void kernel_launch(void* const* d_in, const int* in_sizes, int n_in,
                              void* d_out, int out_size, void* d_ws, size_t ws_size,
                              hipStream_t stream)
{
  (void)in_sizes; (void)n_in; (void)out_size;
  constexpr int Bb = 4, T = 1024, E = 768, D = 768, H = 8;
  constexpr int HD = H * D;                           // 6144
  constexpr long long TD = (long long)T * D;          // 786432
  constexpr long long TT = (long long)T * T;          // 1048576
  constexpr long long DE = (long long)D * E;          // 589824
  constexpr long long DT = (long long)D * T;          // 786432
  constexpr long long BHTD = (long long)Bb * H * T * D;  // 25165824
  constexpr long long HTD = (long long)H * TD;        // 6291456
  constexpr float SCALE = 0.03608439182435161f;       // 1/sqrt(E)

  const float* x  = (const float*)d_in[0];
  const float* wq = (const float*)d_in[1];
  const float* bq = (const float*)d_in[2];
  const float* wk = (const float*)d_in[3];
  const float* bk = (const float*)d_in[4];
  const float* wv = (const float*)d_in[5];
  const float* bv = (const float*)d_in[6];
  const float* wo = (const float*)d_in[7];
  const float* bo = (const float*)d_in[8];
  float* out = (float*)d_out;

  unsigned char* wsb = (unsigned char*)d_ws;
  const dim3 tb32(32, 8);

  // ---- ALL32 tier peak footprint: 245,443,584 B (unchanged) ----
  if (ws_size >= 245443584ULL + 4096ULL) {
    unsigned short* woT   = (unsigned short*)(wsb + 0);            //  9,437,184
    float*          bos   = (float*)(wsb + 9437184);               //      3,072
    float*          bqkv  = (float*)(wsb + 9440256);               //     73,728
    unsigned short* vT    = (unsigned short*)(wsb + 9513984);      // 50,331,648
    unsigned short* qkv   = (unsigned short*)(wsb + 59845632);     // 3x 50,331,648
    unsigned short* q     = qkv;
    unsigned short* k     = qkv + BHTD;
    unsigned short* xb    = (unsigned short*)(wsb + 210840576);    //  6,291,456
    unsigned short* wqkvT = (unsigned short*)(wsb + 217132032);    // 28,311,552
    unsigned short* S     = qkv + 2 * BHTD;   // v region; overlays xb+wqkvT head
    float*          part  = (float*)k;        // 4x12.6MB fits dead k exactly
    unsigned short* z2    = q;                // overlays dead q
    // rowsum/invden live in the dead TAIL of wqkvT (after S ends at 227,617,792)
    float*          rowsum = (float*)(wsb + 227617792);            //  1,048,576
    float*          invden = (float*)(wsb + 228666368);            //    131,072

    // --- prep ---
    convert_f32_bf16_kernel<<<3072, 256, 0, stream>>>(x, xb, Bb * T * E / 4);
    prep_weights_kernel<<<dim3(24, 24, 32), tb32, 0, stream>>>(
        wq, wk, wv, wo, wqkvT, woT);
    bosum_kernel<<<3, 256, 0, stream>>>(bo, bos);
    bconcat_kernel<<<72, 256, 0, stream>>>(bq, bk, bv, bqkv);

    // --- fused QKV: z = proj*8 + h; z>=16 (V) writes vT[b][h][d][t] directly
    gemm_bt_kernel<false><<<dim3(6, 32, 24), 256, 0, stream>>>(
        xb, wqkvT, qkv, bqkv, E, E, E,
        0LL, DE, BHTD, TD, 3, HTD, 10, D, 768LL, 1.0f, vT, nullptr, nullptr);

    // --- E = exp(scale * q k^T) + row partial sums (fused softmax part 1) ---
    gemm_bt_kernel<false><<<dim3(8, 8, 32), 256, 0, stream>>>(
        q, k, S, nullptr, D, D, D,
        TD, TD, TT, 0LL, 0, 0LL, 30, T, 0LL, SCALE, nullptr, rowsum, nullptr);

    // --- invden[z][t] = 1/sum (fused softmax part 2) ---
    invden_kernel<<<128, 256, 0, stream>>>(rowsum, invden);

    // --- z2[b,t,h*D+n] = (E v) * invden : z = b*8+h ---
    gemm_bt_kernel<false><<<dim3(6, 8, 32), 256, 0, stream>>>(
        S, vT, z2, nullptr, T, T, T,
        TT, DT, (long long)T * HD, (long long)D, 3, 0LL, 30, HD, 0LL, 1.0f,
        nullptr, nullptr, invden);

    // --- out-proj split-K=4: partials[kz][4096][768] fp32 ---
    gemm_bt_kernel<true><<<dim3(6, 32, 4), 256, 0, stream>>>(
        z2, woT, part, nullptr, 1536, HD, HD,
        1536LL, 1536LL, 3145728LL, 0LL, 0, 0LL, 30, E, 0LL, 1.0f,
        nullptr, nullptr, nullptr);
    reduce4_kernel<<<3072, 256, 0, stream>>>(part, bos, out, 4096 * 768 / 4);
    return;
  }

  // ---------------- fallback: proven chunked path ----------------
  const size_t FIXED = 84937728ULL;
  const size_t PERCH = 8388608ULL;
  int CH = 8;
  while (CH > 1 && FIXED + (size_t)CH * PERCH > ws_size) CH >>= 1;

  size_t off = 0;
  auto carve = [&](size_t bytes) -> void* {
    void* p = wsb + off;
    off += (bytes + 255) & ~(size_t)255;
    return p;
  };
  unsigned short* xb  = (unsigned short*)carve((size_t)Bb * T * E * 2);
  unsigned short* wqT = (unsigned short*)carve((size_t)H * D * E * 2);
  unsigned short* wkT = (unsigned short*)carve((size_t)H * D * E * 2);
  unsigned short* wvT = (unsigned short*)carve((size_t)H * D * E * 2);
  float*          bos = (float*)carve(E * 4);
  unsigned short* z2  = (unsigned short*)carve((size_t)Bb * T * HD * 2);
  unsigned short* qc  = (unsigned short*)carve((size_t)CH * T * D * 2);
  unsigned short* kc  = (unsigned short*)carve((size_t)CH * T * D * 2);
  unsigned short* vc  = (unsigned short*)carve((size_t)CH * T * D * 2);
  unsigned short* vTc = (unsigned short*)carve((size_t)CH * D * T * 2);
  unsigned short* Sc  = (unsigned short*)carve((size_t)CH * T * T * 2);
  unsigned short* woT = wqT;  // wqT dead after chunk loop

  convert_f32_bf16_kernel<<<3072, 256, 0, stream>>>(x, xb, Bb * T * E / 4);
  transpose_conv_kernel<<<dim3(24, 24, 8), tb32, 0, stream>>>(wq, wqT, E, D);
  transpose_conv_kernel<<<dim3(24, 24, 8), tb32, 0, stream>>>(wk, wkT, E, D);
  transpose_conv_kernel<<<dim3(24, 24, 8), tb32, 0, stream>>>(wv, wvT, E, D);
  bosum_kernel<<<3, 256, 0, stream>>>(bo, bos);

  const int nchunks = (Bb * H) / CH;
  for (int c = 0; c < nchunks; ++c) {
    const int z0 = c * CH;
    const int b  = z0 >> 3;
    const int h0 = z0 & 7;
    const unsigned short* xbb = xb + (size_t)b * T * E;

    gemm_bt_kernel<false><<<dim3(6, 8, CH), 256, 0, stream>>>(
        xbb, wqT + (size_t)h0 * DE, qc, bq + (size_t)h0 * D, E, E, E,
        0LL, DE, TD, 0LL, 0, 0LL, 30, D, (long long)D, 1.0f,
        nullptr, nullptr, nullptr);
    gemm_bt_kernel<false><<<dim3(6, 8, CH), 256, 0, stream>>>(
        xbb, wkT + (size_t)h0 * DE, kc, bk + (size_t)h0 * D, E, E, E,
        0LL, DE, TD, 0LL, 0, 0LL, 30, D, (long long)D, 1.0f,
        nullptr, nullptr, nullptr);
    gemm_bt_kernel<false><<<dim3(6, 8, CH), 256, 0, stream>>>(
        xbb, wvT + (size_t)h0 * DE, vc, bv + (size_t)h0 * D, E, E, E,
        0LL, DE, TD, 0LL, 0, 0LL, 30, D, (long long)D, 1.0f,
        nullptr, nullptr, nullptr);

    transpose_bf16_kernel<<<dim3(24, 32, CH), tb32, 0, stream>>>(vc, vTc, T, D);

    gemm_bt_kernel<false><<<dim3(8, 8, CH), 256, 0, stream>>>(
        qc, kc, Sc, nullptr, D, D, D,
        TD, TD, TT, 0LL, 0, 0LL, 30, T, 0LL, SCALE,
        nullptr, nullptr, nullptr);

    softmax_kernel<<<CH * T, 256, 0, stream>>>(Sc);

    gemm_bt_kernel<false><<<dim3(6, 8, CH), 256, 0, stream>>>(
        Sc, vTc, z2 + (size_t)b * T * HD + (size_t)h0 * D, nullptr, T, T, T,
        TT, DT, (long long)D, 0LL, 0, 0LL, 30, HD, 0LL, 1.0f,
        nullptr, nullptr, nullptr);
  }

  transpose_conv_kernel<<<dim3(24, 192, 1), tb32, 0, stream>>>(wo, woT, HD, E);
  gemm_bt_kernel<true><<<dim3(6, 32, 1), 256, 0, stream>>>(
      z2, woT, out, bos, HD, HD, HD,
      0LL, 0LL, 0LL, 0LL, 0, 0LL, 30, E, 0LL, 1.0f,
      nullptr, nullptr, nullptr);
}